// Round 1
// 492.035 us; speedup vs baseline: 1.0400x; 1.0400x over previous
//
#include <hip/hip_runtime.h>
#include <hip/hip_bf16.h>

typedef unsigned short u16;
typedef unsigned char u8;
typedef __attribute__((ext_vector_type(8))) short bf16x8;
typedef __attribute__((ext_vector_type(4))) float f32x4;
typedef __attribute__((ext_vector_type(2))) float f32x2;

__device__ __forceinline__ float bf2f(u16 u){
  union { unsigned int i; float f; } v; v.i = ((unsigned int)u) << 16; return v.f;
}
__device__ __forceinline__ u16 f2bf(float f){
  union { float f; unsigned int i; } v; v.f = f;
  unsigned int lsb = (v.i >> 16) & 1u;
  v.i += 0x7fffu + lsb;
  return (u16)(v.i >> 16);
}
__device__ __forceinline__ unsigned pkbf(float a, float b){
  __hip_bfloat162 h = __float22bfloat162_rn(make_float2(a, b));
  union { __hip_bfloat162 h2; unsigned u; } c; c.h2 = h; return c.u;
}
__device__ __forceinline__ u8 f2fp8(float f){
  int p = __builtin_amdgcn_cvt_pk_fp8_f32(f, f, 0, false);
  return (u8)(p & 0xFF);
}

// ---------------- dtype sniffer (flag consumed only by edge_mlp) --------------
__global__ void k_sniff(const u16* __restrict__ p, int* __restrict__ flag){
  __shared__ int s[256];
  int tid = threadIdx.x;
  u16 v = p[2 * tid];
  int e = (v >> 7) & 0xFF;
  s[tid] = (e >= 100 && e <= 135) ? 1 : 0;
  __syncthreads();
  for (int off = 128; off; off >>= 1){
    if (tid < off) s[tid] += s[tid + off];
    __syncthreads();
  }
  if (tid == 0) *flag = (s[0] < 180) ? 1 : 0;
}

// ---------------- merged prep v2: flat work-proportional scheduling -----------
// Each block recomputes the dtype flag from h (512B) -> no sniff dependency.
// mode 0: scalar canon  (n elems)     mode 1: uint2 canon (n = groups of 4)
// mode 2: LDS-tiled canon+transpose W[K][256]->WT[256][K]  (one 32x32 tile/blk)
// mode 4: CSR position pass: slot[i] = atomicAdd(&cnt[dst[i]],1)  (n = E)
struct PrepEnt { const void* s; void* d; void* d2; int n; int K; int mode; int bstart; };
struct Prep16 { PrepEnt e[16]; };
__global__ void k_prep(Prep16 tab, const u16* __restrict__ hsrc){
  __shared__ int s[256];
  __shared__ u16 tl[32][33];
  {
    int tid = threadIdx.x;
    u16 v = hsrc[2 * tid];
    int e = (v >> 7) & 0xFF;
    s[tid] = (e >= 100 && e <= 135) ? 1 : 0;
    __syncthreads();
    for (int off = 128; off; off >>= 1){
      if (tid < off) s[tid] += s[tid + off];
      __syncthreads();
    }
  }
  const int flag = (s[0] < 180) ? 1 : 0;
  __syncthreads();

  // flat entry lookup: bstarts strictly increasing, all 16 slots valid
  const int bx = blockIdx.x;
  int y = 0;
  #pragma unroll
  for (int i = 1; i < 16; ++i) if (bx >= tab.e[i].bstart) y = i;
  PrepEnt en = tab.e[y];
  const int nblk = ((y < 15) ? tab.e[y + 1].bstart : (int)gridDim.x) - en.bstart;
  const int lb = bx - en.bstart;
  const int T = nblk * 256;
  const int t0 = lb * 256 + threadIdx.x;

  if (en.mode == 1){
    u16* d = (u16*)en.d;
    for (int i = t0; i < en.n; i += T){
      u16 o[4];
      if (flag){
        float4 v = ((const float4*)en.s)[i];
        o[0] = f2bf(v.x); o[1] = f2bf(v.y); o[2] = f2bf(v.z); o[3] = f2bf(v.w);
      } else {
        uint2 v = ((const uint2*)en.s)[i];
        o[0] = (u16)v.x; o[1] = (u16)(v.x >> 16); o[2] = (u16)v.y; o[3] = (u16)(v.y >> 16);
      }
      uint2 w; w.x = o[0] | ((unsigned)o[1] << 16); w.y = o[2] | ((unsigned)o[3] << 16);
      ((uint2*)d)[i] = w;
    }
  } else if (en.mode == 0){
    u16* d = (u16*)en.d;
    for (int i = t0; i < en.n; i += T){
      if (flag) d[i] = f2bf(((const float*)en.s)[i]);
      else      d[i] = ((const u16*)en.s)[i];
    }
  } else if (en.mode == 2){
    // one 32x32 tile per block; coalesced read AND coalesced write
    u16* wt = (u16*)en.d;
    const int K = en.K;
    const int tk = lb >> 3, tc = lb & 7;            // 8 col-tiles (256 cols)
    const int tx = threadIdx.x & 31, ty = threadIdx.x >> 5;   // ty in 0..7
    #pragma unroll
    for (int r = 0; r < 4; ++r){
      int row = tk * 32 + ty + r * 8, col = tc * 32 + tx;
      u16 b;
      if (flag) b = f2bf(((const float*)en.s)[row * 256 + col]);
      else      b = ((const u16*)en.s)[row * 256 + col];
      tl[ty + r * 8][tx] = b;
    }
    __syncthreads();
    #pragma unroll
    for (int r = 0; r < 4; ++r){
      int c = tc * 32 + ty + r * 8, k = tk * 32 + tx;
      wt[(size_t)c * K + k] = tl[tx][ty + r * 8];
    }
  } else {
    // mode 4: single atomic pass builds BOTH histogram and scatter positions
    const int* dstp = (const int*)en.s;
    int* slotp = (int*)en.d;
    int* cur   = (int*)en.d2;
    for (int base = t0; base < en.n; base += 4 * T){
      int e0 = base, e1 = base + T, e2 = base + 2 * T, e3 = base + 3 * T;
      bool v0 = e0 < en.n, v1 = e1 < en.n, v2 = e2 < en.n, v3 = e3 < en.n;
      int d0 = 0, d1 = 0, d2 = 0, d3 = 0;
      if (v0) d0 = dstp[e0];
      if (v1) d1 = dstp[e1];
      if (v2) d2 = dstp[e2];
      if (v3) d3 = dstp[e3];
      int p0 = 0, p1 = 0, p2 = 0, p3 = 0;
      if (v0) p0 = atomicAdd(&cur[d0], 1);
      if (v1) p1 = atomicAdd(&cur[d1], 1);
      if (v2) p2 = atomicAdd(&cur[d2], 1);
      if (v3) p3 = atomicAdd(&cur[d3], 1);
      if (v0) slotp[e0] = p0;
      if (v1) slotp[e1] = p1;
      if (v2) slotp[e2] = p2;
      if (v3) slotp[e3] = p3;
    }
  }
}

// ---------------- CSR scans ----------------
__global__ void k_scan1(const int* __restrict__ cnt, int* __restrict__ rowptr,
                        int* __restrict__ bsums, int N){
  __shared__ int s[256];
  int i = blockIdx.x * 256 + threadIdx.x;
  int v = (i < N) ? cnt[i] : 0;
  s[threadIdx.x] = v; __syncthreads();
  for (int off = 1; off < 256; off <<= 1){
    int x = 0;
    if (threadIdx.x >= off) x = s[threadIdx.x - off];
    __syncthreads();
    s[threadIdx.x] += x;
    __syncthreads();
  }
  if (i < N) rowptr[i + 1] = s[threadIdx.x];
  if (threadIdx.x == 255) bsums[blockIdx.x] = s[255];
}
__global__ void k_scan2(int* __restrict__ bsums, int nb){
  __shared__ int s[256];
  int t = threadIdx.x;
  int v = (t < nb) ? bsums[t] : 0;
  s[t] = v; __syncthreads();
  for (int off = 1; off < 256; off <<= 1){
    int x = 0;
    if (t >= off) x = s[t - off];
    __syncthreads();
    s[t] += x;
    __syncthreads();
  }
  if (t < nb) bsums[t] = s[t] - v;                // exclusive
}
__global__ void k_scan3(int* __restrict__ rowptr, const int* __restrict__ bsums, int N){
  int i = blockIdx.x * 256 + threadIdx.x;
  if (i < N){
    rowptr[i + 1] += bsums[blockIdx.x];
    if (i == 0) rowptr[0] = 0;
  }
}
// atomic-free CSR placement using precomputed slots
__global__ void k_place(const int* __restrict__ src, const int* __restrict__ dst,
                        const int* __restrict__ slot, const int* __restrict__ rowptr,
                        int4* __restrict__ csrp, int E){
  const int T = gridDim.x * 256;
  for (int i = blockIdx.x * 256 + threadIdx.x; i < E; i += T){
    int d = dst[i];
    csrp[rowptr[d] + slot[i]] = make_int4(src[i], d, i, 0);
  }
}
// coalesced src-extraction: csrs[i] = csrp[i].x
__global__ void k_extract(const int4* __restrict__ csrp, int* __restrict__ csrs, int E){
  int i = blockIdx.x * 256 + threadIdx.x;
  if (i < E) csrs[i] = csrp[i].x;
}

// ---------------- layer-1 merged GEMM: z=0 attn->FT8+el/er, z=1 plain->XA -----
__global__ __launch_bounds__(256, 4) void mfma_gemm_l1(
    const u16* __restrict__ X, const u16* __restrict__ WT, const u16* __restrict__ WTr,
    u8* __restrict__ FT8, u16* __restrict__ XA,
    const u16* __restrict__ al, const u16* __restrict__ ar,
    float* __restrict__ el4, float* __restrict__ er4, int N, int K)
{
  const int wave = threadIdx.x >> 6;
  const int lane = threadIdx.x & 63;
  const int m = lane & 15;
  const int q = lane >> 4;
  const int row0 = blockIdx.x * 128 + wave * 32;
  const int col0 = blockIdx.y * 128;
  f32x4 acc[2][8];
  #pragma unroll
  for (int g = 0; g < 2; ++g)
    #pragma unroll
    for (int t = 0; t < 8; ++t) acc[g][t] = (f32x4){0.f, 0.f, 0.f, 0.f};
  const int rA = row0 + m, rB = row0 + 16 + m;
  const bool vA = rA < N, vB = rB < N;
  const u16* apA = X + (size_t)rA * K + q * 8;
  const u16* apB = X + (size_t)rB * K + q * 8;
  const u16* W = (blockIdx.z == 0) ? WT : WTr;
  for (int k0 = 0; k0 < K; k0 += 32){
    bf16x8 aA = {}, aB = {};
    if (vA) aA = *(const bf16x8*)(apA + k0);
    if (vB) aB = *(const bf16x8*)(apB + k0);
    #pragma unroll
    for (int t = 0; t < 8; ++t){
      const u16* bptr = W + (size_t)(col0 + t * 16 + m) * K + k0 + q * 8;
      bf16x8 b = *(const bf16x8*)bptr;
      acc[0][t] = __builtin_amdgcn_mfma_f32_16x16x32_bf16(aA, b, acc[0][t], 0, 0, 0);
      acc[1][t] = __builtin_amdgcn_mfma_f32_16x16x32_bf16(aB, b, acc[1][t], 0, 0, 0);
    }
  }
  if (blockIdx.z == 0){
    float alv[8], arv[8];
    #pragma unroll
    for (int t = 0; t < 8; ++t){
      alv[t] = bf2f(al[col0 + t * 16 + m]);
      arv[t] = bf2f(ar[col0 + t * 16 + m]);
    }
    #pragma unroll
    for (int g = 0; g < 2; ++g)
      #pragma unroll
      for (int r = 0; r < 4; ++r){
        float pe[2] = {0.f, 0.f}, pr[2] = {0.f, 0.f};
        #pragma unroll
        for (int t = 0; t < 8; ++t){
          pe[t >> 2] += acc[g][t][r] * alv[t];
          pr[t >> 2] += acc[g][t][r] * arv[t];
        }
        #pragma unroll
        for (int mk = 1; mk < 16; mk <<= 1){
          pe[0] += __shfl_xor(pe[0], mk); pe[1] += __shfl_xor(pe[1], mk);
          pr[0] += __shfl_xor(pr[0], mk); pr[1] += __shfl_xor(pr[1], mk);
        }
        int rr = row0 + g * 16 + q * 4 + r;
        if (m == 0 && rr < N){
          *(float2*)(el4 + (size_t)rr * 4 + blockIdx.y * 2) = make_float2(pe[0], pe[1]);
          *(float2*)(er4 + (size_t)rr * 4 + blockIdx.y * 2) = make_float2(pr[0], pr[1]);
        }
      }
    #pragma unroll
    for (int g = 0; g < 2; ++g)
      #pragma unroll
      for (int t = 0; t < 8; ++t){
        int col = col0 + t * 16 + m;
        #pragma unroll
        for (int r = 0; r < 4; ++r){
          int rr = row0 + g * 16 + q * 4 + r;
          if (rr < N) FT8[(size_t)rr * 256 + col] = f2fp8(acc[g][t][r]);
        }
      }
  } else {
    #pragma unroll
    for (int g = 0; g < 2; ++g)
      #pragma unroll
      for (int t = 0; t < 8; ++t){
        int col = col0 + t * 16 + m;
        #pragma unroll
        for (int r = 0; r < 4; ++r){
          int rr = row0 + g * 16 + q * 4 + r;
          if (rr < N) XA[(size_t)rr * 256 + col] = f2bf(acc[g][t][r]);
        }
      }
  }
}

// ---------------- GEMM v3 + fused attention logits, fp8 FT out (layers 2/3) ---
__global__ __launch_bounds__(256, 4) void mfma_gemm_attn3(
    const u16* __restrict__ X, const u16* __restrict__ WT,
    u8* __restrict__ OUT8, const u16* __restrict__ al, const u16* __restrict__ ar,
    float* __restrict__ el4, float* __restrict__ er4, int N, int K)
{
  const int wave = threadIdx.x >> 6;
  const int lane = threadIdx.x & 63;
  const int m = lane & 15;
  const int q = lane >> 4;
  const int row0 = blockIdx.x * 128 + wave * 32;
  const int col0 = blockIdx.y * 128;
  f32x4 acc[2][8];
  #pragma unroll
  for (int g = 0; g < 2; ++g)
    #pragma unroll
    for (int t = 0; t < 8; ++t) acc[g][t] = (f32x4){0.f, 0.f, 0.f, 0.f};
  const int rA = row0 + m, rB = row0 + 16 + m;
  const bool vA = rA < N, vB = rB < N;
  const u16* apA = X + (size_t)rA * K + q * 8;
  const u16* apB = X + (size_t)rB * K + q * 8;
  for (int k0 = 0; k0 < K; k0 += 32){
    bf16x8 aA = {}, aB = {};
    if (vA) aA = *(const bf16x8*)(apA + k0);
    if (vB) aB = *(const bf16x8*)(apB + k0);
    #pragma unroll
    for (int t = 0; t < 8; ++t){
      const u16* bptr = WT + (size_t)(col0 + t * 16 + m) * K + k0 + q * 8;
      bf16x8 b = *(const bf16x8*)bptr;
      acc[0][t] = __builtin_amdgcn_mfma_f32_16x16x32_bf16(aA, b, acc[0][t], 0, 0, 0);
      acc[1][t] = __builtin_amdgcn_mfma_f32_16x16x32_bf16(aB, b, acc[1][t], 0, 0, 0);
    }
  }
  float alv[8], arv[8];
  #pragma unroll
  for (int t = 0; t < 8; ++t){
    alv[t] = bf2f(al[col0 + t * 16 + m]);
    arv[t] = bf2f(ar[col0 + t * 16 + m]);
  }
  #pragma unroll
  for (int g = 0; g < 2; ++g)
    #pragma unroll
    for (int r = 0; r < 4; ++r){
      float pe[2] = {0.f, 0.f}, pr[2] = {0.f, 0.f};
      #pragma unroll
      for (int t = 0; t < 8; ++t){
        pe[t >> 2] += acc[g][t][r] * alv[t];
        pr[t >> 2] += acc[g][t][r] * arv[t];
      }
      #pragma unroll
      for (int mk = 1; mk < 16; mk <<= 1){
        pe[0] += __shfl_xor(pe[0], mk); pe[1] += __shfl_xor(pe[1], mk);
        pr[0] += __shfl_xor(pr[0], mk); pr[1] += __shfl_xor(pr[1], mk);
      }
      int rr = row0 + g * 16 + q * 4 + r;
      if (m == 0 && rr < N){
        *(float2*)(el4 + (size_t)rr * 4 + blockIdx.y * 2) = make_float2(pe[0], pe[1]);
        *(float2*)(er4 + (size_t)rr * 4 + blockIdx.y * 2) = make_float2(pr[0], pr[1]);
      }
    }
  #pragma unroll
  for (int g = 0; g < 2; ++g)
    #pragma unroll
    for (int t = 0; t < 8; ++t){
      int col = col0 + t * 16 + m;
      #pragma unroll
      for (int r = 0; r < 4; ++r){
        int rr = row0 + g * 16 + q * 4 + r;
        if (rr < N) OUT8[(size_t)rr * 256 + col] = f2fp8(acc[g][t][r]);
      }
    }
}

// ---------------- aggregation v7p (r13: the 50.4us local optimum) -------------
__global__ __launch_bounds__(256) void aggregate7(
    const u8* __restrict__ ft8, const float* __restrict__ el4, const float* __restrict__ er4,
    const int* __restrict__ rowptr, const int* __restrict__ csrs,
    const u16* __restrict__ residb, u16* __restrict__ outb,
    u16* __restrict__ hf, int do_hf, int N)
{
  __shared__ float sal[4][64][4];
  __shared__ int   sof[4][64];
  const int w = threadIdx.x >> 6, lane = threadIdx.x & 63;
  const int d = blockIdx.x * 4 + w;
  if (d >= N) return;
  const int beg = rowptr[d], deg = rowptr[d + 1] - beg;
  const int H = lane >> 5;            // edge-parity half
  const int c = lane & 31;            // col group: cols c*8 .. c*8+7
  const int hg = c >> 3;              // head of those cols
  f32x2 acc2[4];
  #pragma unroll
  for (int i = 0; i < 4; ++i) acc2[i] = (f32x2){0.f, 0.f};

  if (deg > 0){
    const float4 erd = ((const float4*)er4)[d];
    const int dc = min(deg, 64);
    float x0 = 0.f, x1 = 0.f, x2 = 0.f, x3 = 0.f; int sc = 0;
    float d0 = 0.f, d1 = 0.f, d2 = 0.f, d3 = 0.f;
    for (int j = lane; j < deg; j += 64){
      int s = csrs[beg + j];
      float4 ql = ((const float4*)el4)[s];
      float e0 = ql.x + erd.x; e0 = (e0 > 0.f) ? e0 : 0.2f * e0;
      float e1 = ql.y + erd.y; e1 = (e1 > 0.f) ? e1 : 0.2f * e1;
      float e2 = ql.z + erd.z; e2 = (e2 > 0.f) ? e2 : 0.2f * e2;
      float e3 = ql.w + erd.w; e3 = (e3 > 0.f) ? e3 : 0.2f * e3;
      float t0 = __expf(fminf(e0, 60.f)), t1 = __expf(fminf(e1, 60.f));
      float t2 = __expf(fminf(e2, 60.f)), t3 = __expf(fminf(e3, 60.f));
      if (j < 64){ x0 = t0; x1 = t1; x2 = t2; x3 = t3; sc = s; }
      d0 += t0; d1 += t1; d2 += t2; d3 += t3;
    }
    for (int mk = 1; mk < dc; mk <<= 1){
      d0 += __shfl_xor(d0, mk); d1 += __shfl_xor(d1, mk);
      d2 += __shfl_xor(d2, mk); d3 += __shfl_xor(d3, mk);
    }
    const float i0 = 1.f / d0, i1 = 1.f / d1, i2 = 1.f / d2, i3 = 1.f / d3;

    for (int c0 = 0; c0 < deg; c0 += 64){
      int cs = min(64, deg - c0);
      if (lane < cs){
        float t0, t1, t2, t3; int s;
        if (c0 == 0){ t0 = x0; t1 = x1; t2 = x2; t3 = x3; s = sc; }
        else {
          s = csrs[beg + c0 + lane];
          float4 ql = ((const float4*)el4)[s];
          float e0 = ql.x + erd.x; e0 = (e0 > 0.f) ? e0 : 0.2f * e0;
          float e1 = ql.y + erd.y; e1 = (e1 > 0.f) ? e1 : 0.2f * e1;
          float e2 = ql.z + erd.z; e2 = (e2 > 0.f) ? e2 : 0.2f * e2;
          float e3 = ql.w + erd.w; e3 = (e3 > 0.f) ? e3 : 0.2f * e3;
          t0 = __expf(fminf(e0, 60.f)); t1 = __expf(fminf(e1, 60.f));
          t2 = __expf(fminf(e2, 60.f)); t3 = __expf(fminf(e3, 60.f));
        }
        sal[w][lane][0] = t0 * i0; sal[w][lane][1] = t1 * i1;
        sal[w][lane][2] = t2 * i2; sal[w][lane][3] = t3 * i3;
        sof[w][lane] = s << 8;                      // s * 256 bytes (fp8 row)
      }
      __builtin_amdgcn_wave_barrier();
      for (int j0 = 0; j0 < cs; j0 += 4){
        int jA = j0 + H, jB = j0 + 2 + H;
        bool bA = jA < cs, bB = jB < cs;
        float aA = 0.f, aB = 0.f;
        int offA = 0, offB = 0;
        if (bA){ aA = sal[w][jA][hg]; offA = sof[w][jA]; }
        if (bB){ aB = sal[w][jB][hg]; offB = sof[w][jB]; }
        uint2 vA = {}, vB = {};
        if (bA) vA = *(const uint2*)(ft8 + (size_t)(unsigned)offA + c * 8);
        if (bB) vB = *(const uint2*)(ft8 + (size_t)(unsigned)offB + c * 8);
        if (bA){
          f32x2 a2 = (f32x2){aA, aA};
          acc2[0] += __builtin_amdgcn_cvt_pk_f32_fp8(vA.x, 0) * a2;
          acc2[1] += __builtin_amdgcn_cvt_pk_f32_fp8(vA.x, 1) * a2;
          acc2[2] += __builtin_amdgcn_cvt_pk_f32_fp8(vA.y, 0) * a2;
          acc2[3] += __builtin_amdgcn_cvt_pk_f32_fp8(vA.y, 1) * a2;
        }
        if (bB){
          f32x2 a2 = (f32x2){aB, aB};
          acc2[0] += __builtin_amdgcn_cvt_pk_f32_fp8(vB.x, 0) * a2;
          acc2[1] += __builtin_amdgcn_cvt_pk_f32_fp8(vB.x, 1) * a2;
          acc2[2] += __builtin_amdgcn_cvt_pk_f32_fp8(vB.y, 0) * a2;
          acc2[3] += __builtin_amdgcn_cvt_pk_f32_fp8(vB.y, 1) * a2;
        }
      }
      __builtin_amdgcn_wave_barrier();
    }
  }
  float acc[8];
  #pragma unroll
  for (int i = 0; i < 4; ++i){ acc[2 * i] = acc2[i].x; acc[2 * i + 1] = acc2[i].y; }
  #pragma unroll
  for (int i = 0; i < 8; ++i) acc[i] += __shfl_xor(acc[i], 32);
  uint4 rv = *(const uint4*)(residb + (size_t)d * 256 + c * 8);
  float rr[8];
  {
    union { unsigned u; float f; } t;
    t.u = rv.x << 16; rr[0] = t.f; t.u = rv.x & 0xffff0000u; rr[1] = t.f;
    t.u = rv.y << 16; rr[2] = t.f; t.u = rv.y & 0xffff0000u; rr[3] = t.f;
    t.u = rv.z << 16; rr[4] = t.f; t.u = rv.z & 0xffff0000u; rr[5] = t.f;
    t.u = rv.w << 16; rr[6] = t.f; t.u = rv.w & 0xffff0000u; rr[7] = t.f;
  }
  if (!do_hf){
    if (H == 0){
      float o[8];
      #pragma unroll
      for (int i = 0; i < 8; ++i) o[i] = fmaxf(acc[i] + rr[i], 0.f);
      uint4 ov;
      ov.x = pkbf(o[0], o[1]); ov.y = pkbf(o[2], o[3]);
      ov.z = pkbf(o[4], o[5]); ov.w = pkbf(o[6], o[7]);
      *(uint4*)(outb + (size_t)d * 256 + c * 8) = ov;
    }
  } else {
    #pragma unroll
    for (int i = 0; i < 8; ++i){
      float o = acc[i] + rr[i];
      o += __shfl_xor(o, 8);
      o += __shfl_xor(o, 16);
      acc[i] = 0.25f * o;
    }
    if (lane < 8){
      uint4 ov;
      ov.x = pkbf(acc[0], acc[1]); ov.y = pkbf(acc[2], acc[3]);
      ov.z = pkbf(acc[4], acc[5]); ov.w = pkbf(acc[6], acc[7]);
      *(uint4*)(hf + (size_t)d * 64 + lane * 8) = ov;
    }
  }
}

// ---------------- MFMA edge MLP, CSR-ordered ----------------------------------
__global__ __launch_bounds__(256) void edge_mlp_csr(
    const u16* __restrict__ hfb, const int4* __restrict__ csrp,
    const u16* __restrict__ Wm1, const u16* __restrict__ bm1,
    const u16* __restrict__ Wm2, const u16* __restrict__ bm2,
    void* __restrict__ out, int E, const int* __restrict__ flag)
{
  const int lane = threadIdx.x & 63;
  const int m = lane & 15;
  const int q = lane >> 4;
  const int is_f32 = *flag;

  bf16x8 bfr[4][2];
  #pragma unroll
  for (int t = 0; t < 4; ++t)
    #pragma unroll
    for (int ks = 0; ks < 2; ++ks)
      #pragma unroll
      for (int j = 0; j < 8; ++j)
        bfr[t][ks][j] = (short)Wm1[(size_t)(ks * 32 + q * 8 + j) * 64 + t * 16 + m];

  float b1v[4], w2v[4];
  #pragma unroll
  for (int t = 0; t < 4; ++t){
    b1v[t] = bf2f(bm1[t * 16 + m]);
    w2v[t] = bf2f(Wm2[t * 16 + m]);
  }
  const float b2 = bf2f(bm2[0]);

  const int wid = blockIdx.x * 4 + (threadIdx.x >> 6);
  const int nw  = gridDim.x * 4;
  for (int e0 = wid * 16; e0 < E; e0 += nw * 16){
    int e = e0 + m; if (e >= E) e = E - 1;
    int4 ed = csrp[e];
    const u16* ps = hfb + (size_t)ed.x * 64;
    const u16* pd = hfb + (size_t)ed.y * 64;
    union { bf16x8 v; uint4 u; } af[2];
    #pragma unroll
    for (int ks = 0; ks < 2; ++ks){
      bf16x8 vs = *(const bf16x8*)(ps + ks * 32 + q * 8);
      bf16x8 vd = *(const bf16x8*)(pd + ks * 32 + q * 8);
      unsigned pk[4];
      #pragma unroll
      for (int pp = 0; pp < 4; ++pp){
        float a0 = fabsf(bf2f((u16)vs[2 * pp])     - bf2f((u16)vd[2 * pp]));
        float a1 = fabsf(bf2f((u16)vs[2 * pp + 1]) - bf2f((u16)vd[2 * pp + 1]));
        pk[pp] = pkbf(a0, a1);
      }
      af[ks].u = make_uint4(pk[0], pk[1], pk[2], pk[3]);
    }
    f32x4 acc[4];
    #pragma unroll
    for (int t = 0; t < 4; ++t) acc[t] = (f32x4){0.f, 0.f, 0.f, 0.f};
    #pragma unroll
    for (int ks = 0; ks < 2; ++ks)
      #pragma unroll
      for (int t = 0; t < 4; ++t)
        acc[t] = __builtin_amdgcn_mfma_f32_16x16x32_bf16(af[ks].v, bfr[t][ks], acc[t], 0, 0, 0);
    #pragma unroll
    for (int r = 0; r < 4; ++r){
      float p = 0.f;
      #pragma unroll
      for (int t = 0; t < 4; ++t)
        p += fmaxf(acc[t][r] + b1v[t], 0.f) * w2v[t];
      #pragma unroll
      for (int mm = 1; mm < 16; mm <<= 1) p += __shfl_xor(p, mm);
      int slot = e0 + q * 4 + r;
      if (m == 0 && slot < E){
        int eid = csrp[slot].z;
        float sc = 1.f / (1.f + __expf(-(p + b2)));
        if (is_f32) ((float*)out)[eid] = sc;
        else        ((u16*)out)[eid]   = f2bf(sc);
      }
    }
  }
}

extern "C" void kernel_launch(void* const* d_in, const int* in_sizes, int n_in,
                              void* d_out, int out_size, void* d_ws, size_t ws_size,
                              hipStream_t stream)
{
  const int* src = (const int*)d_in[1];
  const int* dst = (const int*)d_in[2];

  const int N = in_sizes[0] / 128;
  const int E = in_sizes[1];

  char* p = (char*)d_ws;
  auto alloc = [&](size_t bytes) -> char* {
    char* r = p; p += (bytes + 255) & ~(size_t)255; return r;
  };
  int* flag   = (int*)  alloc(4);
  u16* hc     = (u16*)  alloc((size_t)N * 128 * 2);
  u8*  FT8    = (u8*)   alloc((size_t)N * 256);
  u16* XA     = (u16*)  alloc((size_t)N * 256 * 2);
  u16* XB     = (u16*)  alloc((size_t)N * 256 * 2);
  float* el   = (float*)alloc((size_t)N * 4 * 4);
  float* er   = (float*)alloc((size_t)N * 4 * 4);
  u16* hfb    = (u16*)  alloc((size_t)N * 64 * 2);
  int* rowptr = (int*)  alloc((size_t)(N + 1) * 4);
  int* cursor = (int*)  alloc((size_t)N * 4);
  int* slot   = (int*)  alloc((size_t)E * 4);
  int4* csrp  = (int4*) alloc((size_t)E * 16);
  int* csrs   = (int*)  alloc((size_t)E * 4);
  int* bsums  = (int*)  alloc(1024);
  u16* WT1    = (u16*)  alloc(128 * 256 * 2);
  u16* WTr1   = (u16*)  alloc(128 * 256 * 2);
  u16* WT2    = (u16*)  alloc(256 * 256 * 2);
  u16* WT3    = (u16*)  alloc(256 * 256 * 2);
  u16* al1c   = (u16*)  alloc(256 * 2);
  u16* ar1c   = (u16*)  alloc(256 * 2);
  u16* al2c   = (u16*)  alloc(256 * 2);
  u16* ar2c   = (u16*)  alloc(256 * 2);
  u16* al3c   = (u16*)  alloc(256 * 2);
  u16* ar3c   = (u16*)  alloc(256 * 2);
  u16* Wm1c   = (u16*)  alloc(4096 * 2);
  u16* bm1c   = (u16*)  alloc(64 * 2);
  u16* Wm2c   = (u16*)  alloc(64 * 2);
  u16* bm2c   = (u16*)  alloc(2);

  const int nb = (N + 255) / 256;
  const int ge = (E + 255) / 256;
  const u16* hsrc = (const u16*)d_in[0];

  // flag for edge_mlp's output dtype (nothing else depends on it)
  k_sniff<<<1, 256, 0, stream>>>(hsrc, flag);
  hipMemsetAsync(cursor, 0, (size_t)N * 4, stream);

  // merged prep: canon + LDS transposes + single-atomic-pass CSR positions
  {
    // work-proportional flat block schedule; atomic pass dispatched first
    Prep16 t{};
    int b = 0;
    auto put = [&](int idx, const void* s, void* d, void* d2, int n, int K,
                   int mode, int nblk){
      t.e[idx] = {s, d, d2, n, K, mode, b};
      b += nblk;
    };
    put(0,  dst,      slot,  cursor, E,         0,   4, 1024);  // CSR positions
    put(1,  d_in[0],  hc,    nullptr, N * 32,   0,   1, 768);   // h canon (uint2)
    put(2,  d_in[3],  WT1,   nullptr, 0,        128, 2, 32);    // 32 tiles
    put(3,  d_in[4],  WTr1,  nullptr, 0,        128, 2, 32);
    put(4,  d_in[7],  WT2,   nullptr, 0,        256, 2, 64);    // 64 tiles
    put(5,  d_in[10], WT3,   nullptr, 0,        256, 2, 64);
    put(6,  d_in[5],  al1c,  nullptr, 256,      0,   0, 1);
    put(7,  d_in[6],  ar1c,  nullptr, 256,      0,   0, 1);
    put(8,  d_in[8],  al2c,  nullptr, 256,      0,   0, 1);
    put(9,  d_in[9],  ar2c,  nullptr, 256,      0,   0, 1);
    put(10, d_in[11], al3c,  nullptr, 256,      0,   0, 1);
    put(11, d_in[12], ar3c,  nullptr, 256,      0,   0, 1);
    put(12, d_in[13], Wm1c,  nullptr, 4096,     0,   0, 1);
    put(13, d_in[14], bm1c,  nullptr, 64,       0,   0, 1);
    put(14, d_in[15], Wm2c,  nullptr, 64,       0,   0, 1);
    put(15, d_in[16], bm2c,  nullptr, 1,        0,   0, 1);
    k_prep<<<dim3(b), 256, 0, stream>>>(t, hsrc);
  }

  // CSR scans + atomic-free placement
  k_scan1<<<nb, 256, 0, stream>>>(cursor, rowptr, bsums, N);
  k_scan2<<<1, 256, 0, stream>>>(bsums, nb);
  k_scan3<<<nb, 256, 0, stream>>>(rowptr, bsums, N);
  k_place<<<512, 256, 0, stream>>>(src, dst, slot, rowptr, csrp, E);
  k_extract<<<ge, 256, 0, stream>>>(csrp, csrs, E);

  const dim3 gA3((N + 127) / 128, 2);
  const dim3 gL1((N + 127) / 128, 2, 2);
  const int gG = (N + 3) / 4;
  // layer 1 (both GEMMs in one launch via grid.z)
  mfma_gemm_l1<<<gL1, 256, 0, stream>>>(hc, WT1, WTr1, FT8, XA, al1c, ar1c, el, er, N, 128);
  aggregate7<<<gG, 256, 0, stream>>>(FT8, el, er, rowptr, csrs, XA, XB, nullptr, 0, N);
  // layer 2
  mfma_gemm_attn3<<<gA3, 256, 0, stream>>>(XB, WT2, FT8, al2c, ar2c, el, er, N, 256);
  aggregate7<<<gG, 256, 0, stream>>>(FT8, el, er, rowptr, csrs, XB, XA, nullptr, 0, N);
  // layer 3 (fused head-mean -> hf bf16)
  mfma_gemm_attn3<<<gA3, 256, 0, stream>>>(XA, WT3, FT8, al3c, ar3c, el, er, N, 256);
  aggregate7<<<gG, 256, 0, stream>>>(FT8, el, er, rowptr, csrs, XA, nullptr, hfb, 1, N);
  // edge MLP (MFMA, CSR-ordered for dst-row locality)
  edge_mlp_csr<<<2048, 256, 0, stream>>>(hfb, csrp, Wm1c, bm1c, Wm2c, bm2c,
                                         d_out, E, flag);
}

// Round 2
// 419.739 us; speedup vs baseline: 1.2191x; 1.1722x over previous
//
#include <hip/hip_runtime.h>
#include <hip/hip_bf16.h>

typedef unsigned short u16;
typedef unsigned char u8;
typedef __attribute__((ext_vector_type(8))) short bf16x8;
typedef __attribute__((ext_vector_type(4))) float f32x4;
typedef __attribute__((ext_vector_type(2))) float f32x2;

__device__ __forceinline__ float bf2f(u16 u){
  union { unsigned int i; float f; } v; v.i = ((unsigned int)u) << 16; return v.f;
}
__device__ __forceinline__ u16 f2bf(float f){
  union { float f; unsigned int i; } v; v.f = f;
  unsigned int lsb = (v.i >> 16) & 1u;
  v.i += 0x7fffu + lsb;
  return (u16)(v.i >> 16);
}
__device__ __forceinline__ unsigned pkbf(float a, float b){
  __hip_bfloat162 h = __float22bfloat162_rn(make_float2(a, b));
  union { __hip_bfloat162 h2; unsigned u; } c; c.h2 = h; return c.u;
}
__device__ __forceinline__ u8 f2fp8(float f){
  int p = __builtin_amdgcn_cvt_pk_fp8_f32(f, f, 0, false);
  return (u8)(p & 0xFF);
}

// ---------------- dtype sniffer (flag consumed only by edge_mlp) --------------
__global__ void k_sniff(const u16* __restrict__ p, int* __restrict__ flag){
  __shared__ int s[256];
  int tid = threadIdx.x;
  u16 v = p[2 * tid];
  int e = (v >> 7) & 0xFF;
  s[tid] = (e >= 100 && e <= 135) ? 1 : 0;
  __syncthreads();
  for (int off = 128; off; off >>= 1){
    if (tid < off) s[tid] += s[tid + off];
    __syncthreads();
  }
  if (tid == 0) *flag = (s[0] < 180) ? 1 : 0;
}

// ---------------- merged prep v2: flat work-proportional scheduling -----------
struct PrepEnt { const void* s; void* d; void* d2; int n; int K; int mode; int bstart; };
struct Prep16 { PrepEnt e[16]; };
__global__ void k_prep(Prep16 tab, const u16* __restrict__ hsrc){
  __shared__ int s[256];
  __shared__ u16 tl[32][33];
  {
    int tid = threadIdx.x;
    u16 v = hsrc[2 * tid];
    int e = (v >> 7) & 0xFF;
    s[tid] = (e >= 100 && e <= 135) ? 1 : 0;
    __syncthreads();
    for (int off = 128; off; off >>= 1){
      if (tid < off) s[tid] += s[tid + off];
      __syncthreads();
    }
  }
  const int flag = (s[0] < 180) ? 1 : 0;
  __syncthreads();

  const int bx = blockIdx.x;
  int y = 0;
  #pragma unroll
  for (int i = 1; i < 16; ++i) if (bx >= tab.e[i].bstart) y = i;
  PrepEnt en = tab.e[y];
  const int nblk = ((y < 15) ? tab.e[y + 1].bstart : (int)gridDim.x) - en.bstart;
  const int lb = bx - en.bstart;
  const int T = nblk * 256;
  const int t0 = lb * 256 + threadIdx.x;

  if (en.mode == 1){
    u16* d = (u16*)en.d;
    for (int i = t0; i < en.n; i += T){
      u16 o[4];
      if (flag){
        float4 v = ((const float4*)en.s)[i];
        o[0] = f2bf(v.x); o[1] = f2bf(v.y); o[2] = f2bf(v.z); o[3] = f2bf(v.w);
      } else {
        uint2 v = ((const uint2*)en.s)[i];
        o[0] = (u16)v.x; o[1] = (u16)(v.x >> 16); o[2] = (u16)v.y; o[3] = (u16)(v.y >> 16);
      }
      uint2 w; w.x = o[0] | ((unsigned)o[1] << 16); w.y = o[2] | ((unsigned)o[3] << 16);
      ((uint2*)d)[i] = w;
    }
  } else if (en.mode == 0){
    u16* d = (u16*)en.d;
    for (int i = t0; i < en.n; i += T){
      if (flag) d[i] = f2bf(((const float*)en.s)[i]);
      else      d[i] = ((const u16*)en.s)[i];
    }
  } else if (en.mode == 2){
    // one 32x32 tile per block; coalesced read AND coalesced write
    u16* wt = (u16*)en.d;
    const int K = en.K;
    const int tk = lb >> 3, tc = lb & 7;
    const int tx = threadIdx.x & 31, ty = threadIdx.x >> 5;
    #pragma unroll
    for (int r = 0; r < 4; ++r){
      int row = tk * 32 + ty + r * 8, col = tc * 32 + tx;
      u16 b;
      if (flag) b = f2bf(((const float*)en.s)[row * 256 + col]);
      else      b = ((const u16*)en.s)[row * 256 + col];
      tl[ty + r * 8][tx] = b;
    }
    __syncthreads();
    #pragma unroll
    for (int r = 0; r < 4; ++r){
      int c = tc * 32 + ty + r * 8, k = tk * 32 + tx;
      wt[(size_t)c * K + k] = tl[tx][ty + r * 8];
    }
  } else {
    // mode 4: single atomic pass builds BOTH histogram and scatter positions
    const int* dstp = (const int*)en.s;
    int* slotp = (int*)en.d;
    int* cur   = (int*)en.d2;
    for (int base = t0; base < en.n; base += 4 * T){
      int e0 = base, e1 = base + T, e2 = base + 2 * T, e3 = base + 3 * T;
      bool v0 = e0 < en.n, v1 = e1 < en.n, v2 = e2 < en.n, v3 = e3 < en.n;
      int d0 = 0, d1 = 0, d2 = 0, d3 = 0;
      if (v0) d0 = dstp[e0];
      if (v1) d1 = dstp[e1];
      if (v2) d2 = dstp[e2];
      if (v3) d3 = dstp[e3];
      int p0 = 0, p1 = 0, p2 = 0, p3 = 0;
      if (v0) p0 = atomicAdd(&cur[d0], 1);
      if (v1) p1 = atomicAdd(&cur[d1], 1);
      if (v2) p2 = atomicAdd(&cur[d2], 1);
      if (v3) p3 = atomicAdd(&cur[d3], 1);
      if (v0) slotp[e0] = p0;
      if (v1) slotp[e1] = p1;
      if (v2) slotp[e2] = p2;
      if (v3) slotp[e3] = p3;
    }
  }
}

// ---------------- CSR scans ----------------
__global__ void k_scan1(const int* __restrict__ cnt, int* __restrict__ rowptr,
                        int* __restrict__ bsums, int N){
  __shared__ int s[256];
  int i = blockIdx.x * 256 + threadIdx.x;
  int v = (i < N) ? cnt[i] : 0;
  s[threadIdx.x] = v; __syncthreads();
  for (int off = 1; off < 256; off <<= 1){
    int x = 0;
    if (threadIdx.x >= off) x = s[threadIdx.x - off];
    __syncthreads();
    s[threadIdx.x] += x;
    __syncthreads();
  }
  if (i < N) rowptr[i + 1] = s[threadIdx.x];
  if (threadIdx.x == 255) bsums[blockIdx.x] = s[255];
}
__global__ void k_scan2(int* __restrict__ bsums, int nb){
  __shared__ int s[256];
  int t = threadIdx.x;
  int v = (t < nb) ? bsums[t] : 0;
  s[t] = v; __syncthreads();
  for (int off = 1; off < 256; off <<= 1){
    int x = 0;
    if (t >= off) x = s[t - off];
    __syncthreads();
    s[t] += x;
    __syncthreads();
  }
  if (t < nb) bsums[t] = s[t] - v;                // exclusive
}
__global__ void k_scan3(int* __restrict__ rowptr, const int* __restrict__ bsums, int N){
  int i = blockIdx.x * 256 + threadIdx.x;
  if (i < N){
    rowptr[i + 1] += bsums[blockIdx.x];
    if (i == 0) rowptr[0] = 0;
  }
}
// atomic-free CSR placement using precomputed slots
__global__ void k_place(const int* __restrict__ src, const int* __restrict__ dst,
                        const int* __restrict__ slot, const int* __restrict__ rowptr,
                        int4* __restrict__ csrp, int E){
  const int T = gridDim.x * 256;
  for (int i = blockIdx.x * 256 + threadIdx.x; i < E; i += T){
    int d = dst[i];
    csrp[rowptr[d] + slot[i]] = make_int4(src[i], d, i, 0);
  }
}
// coalesced src-extraction: csrs[i] = csrp[i].x
__global__ void k_extract(const int4* __restrict__ csrp, int* __restrict__ csrs, int E){
  int i = blockIdx.x * 256 + threadIdx.x;
  if (i < E) csrs[i] = csrp[i].x;
}

// ---------------- unified LDS-staged GEMM (v4) --------------------------------
// Stages B[col0..col0+127][0..K) into LDS once (global_load_lds, width 16),
// slot-XOR-swizzled (slot' = slot ^ (col&7)) so the 16-m-lane ds_read_b128
// fans out across all bank-quads (row stride 256/512B would be 16-way conflict).
// blockIdx.z==1 (layer-1 residual GEMM): plain bf16 out to XA.
// blockIdx.z==0: attn epilogue -> FT8 fp8 + el/er.
__global__ __launch_bounds__(256, 4) void mfma_gemm_v4(
    const u16* __restrict__ X, const u16* __restrict__ WT, const u16* __restrict__ WTr,
    u8* __restrict__ FT8, u16* __restrict__ XA,
    const u16* __restrict__ al, const u16* __restrict__ ar,
    float* __restrict__ el4, float* __restrict__ er4, int N, int K)
{
  extern __shared__ u16 Bs[];                 // 128 * K * 2 bytes (32/64 KB)
  const int wv = threadIdx.x >> 6;
  const int lane = threadIdx.x & 63;
  const int m = lane & 15;
  const int q = lane >> 4;
  const int row0 = blockIdx.x * 128 + wv * 32;
  const int col0 = blockIdx.y * 128;
  const u16* W = (blockIdx.z == 0) ? WT : WTr;

  // ---- stage B into LDS (linear dest, pre-swizzled global source) ----
  {
    const int spr = K >> 3;                   // 16B slots per row (16 or 32)
    const int ish = (spr == 32) ? 5 : 4;
    const int nIss = K >> 4;                  // issues per thread (8 or 16)
    for (int j = 0; j < nIss; ++j){
      int cbase = (j * 4 + wv) * 64;          // wave-uniform chunk base
      int chunk = cbase + lane;
      int col = chunk >> ish;
      int slot = chunk & (spr - 1);
      int gslot = slot ^ (col & 7);
      const u16* srcp = W + (size_t)(col0 + col) * K + gslot * 8;
      u16* dstp = Bs + (size_t)cbase * 8;     // wave-uniform; HW adds lane*16
      __builtin_amdgcn_global_load_lds((const unsigned int*)srcp,
                                       (unsigned int*)dstp, 16, 0, 0);
    }
  }

  f32x4 acc[2][8];
  #pragma unroll
  for (int g = 0; g < 2; ++g)
    #pragma unroll
    for (int t = 0; t < 8; ++t) acc[g][t] = (f32x4){0.f, 0.f, 0.f, 0.f};
  const int rA = row0 + m, rB = row0 + 16 + m;
  const bool vA = rA < N, vB = rB < N;
  const u16* apA = X + (size_t)rA * K + q * 8;
  const u16* apB = X + (size_t)rB * K + q * 8;

  asm volatile("s_waitcnt vmcnt(0)" ::: "memory");
  __syncthreads();

  const int mh = m & 7;
  // barrier-free main loop: B via ds_read_b128, A streamed from global
  for (int k0 = 0; k0 < K; k0 += 32){
    bf16x8 aA = {}, aB = {};
    if (vA) aA = *(const bf16x8*)(apA + k0);
    if (vB) aB = *(const bf16x8*)(apB + k0);
    const int sb = (k0 >> 3) + q;             // linear slot for this lane
    #pragma unroll
    for (int t = 0; t < 8; ++t){
      const u16* bp = Bs + (size_t)(t * 16 + m) * K + (size_t)(sb ^ mh) * 8;
      bf16x8 b = *(const bf16x8*)bp;
      acc[0][t] = __builtin_amdgcn_mfma_f32_16x16x32_bf16(aA, b, acc[0][t], 0, 0, 0);
      acc[1][t] = __builtin_amdgcn_mfma_f32_16x16x32_bf16(aB, b, acc[1][t], 0, 0, 0);
    }
  }

  if (blockIdx.z == 0){
    float alv[8], arv[8];
    #pragma unroll
    for (int t = 0; t < 8; ++t){
      alv[t] = bf2f(al[col0 + t * 16 + m]);
      arv[t] = bf2f(ar[col0 + t * 16 + m]);
    }
    #pragma unroll
    for (int g = 0; g < 2; ++g)
      #pragma unroll
      for (int r = 0; r < 4; ++r){
        float pe[2] = {0.f, 0.f}, pr[2] = {0.f, 0.f};
        #pragma unroll
        for (int t = 0; t < 8; ++t){
          pe[t >> 2] += acc[g][t][r] * alv[t];
          pr[t >> 2] += acc[g][t][r] * arv[t];
        }
        #pragma unroll
        for (int mk = 1; mk < 16; mk <<= 1){
          pe[0] += __shfl_xor(pe[0], mk); pe[1] += __shfl_xor(pe[1], mk);
          pr[0] += __shfl_xor(pr[0], mk); pr[1] += __shfl_xor(pr[1], mk);
        }
        int rr = row0 + g * 16 + q * 4 + r;
        if (m == 0 && rr < N){
          *(float2*)(el4 + (size_t)rr * 4 + blockIdx.y * 2) = make_float2(pe[0], pe[1]);
          *(float2*)(er4 + (size_t)rr * 4 + blockIdx.y * 2) = make_float2(pr[0], pr[1]);
        }
      }
    #pragma unroll
    for (int g = 0; g < 2; ++g)
      #pragma unroll
      for (int t = 0; t < 8; ++t){
        int col = col0 + t * 16 + m;
        #pragma unroll
        for (int r = 0; r < 4; ++r){
          int rr = row0 + g * 16 + q * 4 + r;
          if (rr < N) FT8[(size_t)rr * 256 + col] = f2fp8(acc[g][t][r]);
        }
      }
  } else {
    #pragma unroll
    for (int g = 0; g < 2; ++g)
      #pragma unroll
      for (int t = 0; t < 8; ++t){
        int col = col0 + t * 16 + m;
        #pragma unroll
        for (int r = 0; r < 4; ++r){
          int rr = row0 + g * 16 + q * 4 + r;
          if (rr < N) XA[(size_t)rr * 256 + col] = f2bf(acc[g][t][r]);
        }
      }
  }
}

// ---------------- aggregation v7p (r13: the 50.4us local optimum) -------------
__global__ __launch_bounds__(256) void aggregate7(
    const u8* __restrict__ ft8, const float* __restrict__ el4, const float* __restrict__ er4,
    const int* __restrict__ rowptr, const int* __restrict__ csrs,
    const u16* __restrict__ residb, u16* __restrict__ outb,
    u16* __restrict__ hf, int do_hf, int N)
{
  __shared__ float sal[4][64][4];
  __shared__ int   sof[4][64];
  const int w = threadIdx.x >> 6, lane = threadIdx.x & 63;
  const int d = blockIdx.x * 4 + w;
  if (d >= N) return;
  const int beg = rowptr[d], deg = rowptr[d + 1] - beg;
  const int H = lane >> 5;            // edge-parity half
  const int c = lane & 31;            // col group: cols c*8 .. c*8+7
  const int hg = c >> 3;              // head of those cols
  f32x2 acc2[4];
  #pragma unroll
  for (int i = 0; i < 4; ++i) acc2[i] = (f32x2){0.f, 0.f};

  if (deg > 0){
    const float4 erd = ((const float4*)er4)[d];
    const int dc = min(deg, 64);
    float x0 = 0.f, x1 = 0.f, x2 = 0.f, x3 = 0.f; int sc = 0;
    float d0 = 0.f, d1 = 0.f, d2 = 0.f, d3 = 0.f;
    for (int j = lane; j < deg; j += 64){
      int s = csrs[beg + j];
      float4 ql = ((const float4*)el4)[s];
      float e0 = ql.x + erd.x; e0 = (e0 > 0.f) ? e0 : 0.2f * e0;
      float e1 = ql.y + erd.y; e1 = (e1 > 0.f) ? e1 : 0.2f * e1;
      float e2 = ql.z + erd.z; e2 = (e2 > 0.f) ? e2 : 0.2f * e2;
      float e3 = ql.w + erd.w; e3 = (e3 > 0.f) ? e3 : 0.2f * e3;
      float t0 = __expf(fminf(e0, 60.f)), t1 = __expf(fminf(e1, 60.f));
      float t2 = __expf(fminf(e2, 60.f)), t3 = __expf(fminf(e3, 60.f));
      if (j < 64){ x0 = t0; x1 = t1; x2 = t2; x3 = t3; sc = s; }
      d0 += t0; d1 += t1; d2 += t2; d3 += t3;
    }
    for (int mk = 1; mk < dc; mk <<= 1){
      d0 += __shfl_xor(d0, mk); d1 += __shfl_xor(d1, mk);
      d2 += __shfl_xor(d2, mk); d3 += __shfl_xor(d3, mk);
    }
    const float i0 = 1.f / d0, i1 = 1.f / d1, i2 = 1.f / d2, i3 = 1.f / d3;

    for (int c0 = 0; c0 < deg; c0 += 64){
      int cs = min(64, deg - c0);
      if (lane < cs){
        float t0, t1, t2, t3; int s;
        if (c0 == 0){ t0 = x0; t1 = x1; t2 = x2; t3 = x3; s = sc; }
        else {
          s = csrs[beg + c0 + lane];
          float4 ql = ((const float4*)el4)[s];
          float e0 = ql.x + erd.x; e0 = (e0 > 0.f) ? e0 : 0.2f * e0;
          float e1 = ql.y + erd.y; e1 = (e1 > 0.f) ? e1 : 0.2f * e1;
          float e2 = ql.z + erd.z; e2 = (e2 > 0.f) ? e2 : 0.2f * e2;
          float e3 = ql.w + erd.w; e3 = (e3 > 0.f) ? e3 : 0.2f * e3;
          t0 = __expf(fminf(e0, 60.f)); t1 = __expf(fminf(e1, 60.f));
          t2 = __expf(fminf(e2, 60.f)); t3 = __expf(fminf(e3, 60.f));
        }
        sal[w][lane][0] = t0 * i0; sal[w][lane][1] = t1 * i1;
        sal[w][lane][2] = t2 * i2; sal[w][lane][3] = t3 * i3;
        sof[w][lane] = s << 8;                      // s * 256 bytes (fp8 row)
      }
      __builtin_amdgcn_wave_barrier();
      for (int j0 = 0; j0 < cs; j0 += 4){
        int jA = j0 + H, jB = j0 + 2 + H;
        bool bA = jA < cs, bB = jB < cs;
        float aA = 0.f, aB = 0.f;
        int offA = 0, offB = 0;
        if (bA){ aA = sal[w][jA][hg]; offA = sof[w][jA]; }
        if (bB){ aB = sal[w][jB][hg]; offB = sof[w][jB]; }
        uint2 vA = {}, vB = {};
        if (bA) vA = *(const uint2*)(ft8 + (size_t)(unsigned)offA + c * 8);
        if (bB) vB = *(const uint2*)(ft8 + (size_t)(unsigned)offB + c * 8);
        if (bA){
          f32x2 a2 = (f32x2){aA, aA};
          acc2[0] += __builtin_amdgcn_cvt_pk_f32_fp8(vA.x, 0) * a2;
          acc2[1] += __builtin_amdgcn_cvt_pk_f32_fp8(vA.x, 1) * a2;
          acc2[2] += __builtin_amdgcn_cvt_pk_f32_fp8(vA.y, 0) * a2;
          acc2[3] += __builtin_amdgcn_cvt_pk_f32_fp8(vA.y, 1) * a2;
        }
        if (bB){
          f32x2 a2 = (f32x2){aB, aB};
          acc2[0] += __builtin_amdgcn_cvt_pk_f32_fp8(vB.x, 0) * a2;
          acc2[1] += __builtin_amdgcn_cvt_pk_f32_fp8(vB.x, 1) * a2;
          acc2[2] += __builtin_amdgcn_cvt_pk_f32_fp8(vB.y, 0) * a2;
          acc2[3] += __builtin_amdgcn_cvt_pk_f32_fp8(vB.y, 1) * a2;
        }
      }
      __builtin_amdgcn_wave_barrier();
    }
  }
  float acc[8];
  #pragma unroll
  for (int i = 0; i < 4; ++i){ acc[2 * i] = acc2[i].x; acc[2 * i + 1] = acc2[i].y; }
  #pragma unroll
  for (int i = 0; i < 8; ++i) acc[i] += __shfl_xor(acc[i], 32);
  uint4 rv = *(const uint4*)(residb + (size_t)d * 256 + c * 8);
  float rr[8];
  {
    union { unsigned u; float f; } t;
    t.u = rv.x << 16; rr[0] = t.f; t.u = rv.x & 0xffff0000u; rr[1] = t.f;
    t.u = rv.y << 16; rr[2] = t.f; t.u = rv.y & 0xffff0000u; rr[3] = t.f;
    t.u = rv.z << 16; rr[4] = t.f; t.u = rv.z & 0xffff0000u; rr[5] = t.f;
    t.u = rv.w << 16; rr[6] = t.f; t.u = rv.w & 0xffff0000u; rr[7] = t.f;
  }
  if (!do_hf){
    if (H == 0){
      float o[8];
      #pragma unroll
      for (int i = 0; i < 8; ++i) o[i] = fmaxf(acc[i] + rr[i], 0.f);
      uint4 ov;
      ov.x = pkbf(o[0], o[1]); ov.y = pkbf(o[2], o[3]);
      ov.z = pkbf(o[4], o[5]); ov.w = pkbf(o[6], o[7]);
      *(uint4*)(outb + (size_t)d * 256 + c * 8) = ov;
    }
  } else {
    #pragma unroll
    for (int i = 0; i < 8; ++i){
      float o = acc[i] + rr[i];
      o += __shfl_xor(o, 8);
      o += __shfl_xor(o, 16);
      acc[i] = 0.25f * o;
    }
    if (lane < 8){
      uint4 ov;
      ov.x = pkbf(acc[0], acc[1]); ov.y = pkbf(acc[2], acc[3]);
      ov.z = pkbf(acc[4], acc[5]); ov.w = pkbf(acc[6], acc[7]);
      *(uint4*)(hf + (size_t)d * 64 + lane * 8) = ov;
    }
  }
}

// ---------------- MFMA edge MLP, CSR-ordered ----------------------------------
__global__ __launch_bounds__(256) void edge_mlp_csr(
    const u16* __restrict__ hfb, const int4* __restrict__ csrp,
    const u16* __restrict__ Wm1, const u16* __restrict__ bm1,
    const u16* __restrict__ Wm2, const u16* __restrict__ bm2,
    void* __restrict__ out, int E, const int* __restrict__ flag)
{
  const int lane = threadIdx.x & 63;
  const int m = lane & 15;
  const int q = lane >> 4;
  const int is_f32 = *flag;

  bf16x8 bfr[4][2];
  #pragma unroll
  for (int t = 0; t < 4; ++t)
    #pragma unroll
    for (int ks = 0; ks < 2; ++ks)
      #pragma unroll
      for (int j = 0; j < 8; ++j)
        bfr[t][ks][j] = (short)Wm1[(size_t)(ks * 32 + q * 8 + j) * 64 + t * 16 + m];

  float b1v[4], w2v[4];
  #pragma unroll
  for (int t = 0; t < 4; ++t){
    b1v[t] = bf2f(bm1[t * 16 + m]);
    w2v[t] = bf2f(Wm2[t * 16 + m]);
  }
  const float b2 = bf2f(bm2[0]);

  const int wid = blockIdx.x * 4 + (threadIdx.x >> 6);
  const int nw  = gridDim.x * 4;
  for (int e0 = wid * 16; e0 < E; e0 += nw * 16){
    int e = e0 + m; if (e >= E) e = E - 1;
    int4 ed = csrp[e];
    const u16* ps = hfb + (size_t)ed.x * 64;
    const u16* pd = hfb + (size_t)ed.y * 64;
    union { bf16x8 v; uint4 u; } af[2];
    #pragma unroll
    for (int ks = 0; ks < 2; ++ks){
      bf16x8 vs = *(const bf16x8*)(ps + ks * 32 + q * 8);
      bf16x8 vd = *(const bf16x8*)(pd + ks * 32 + q * 8);
      unsigned pk[4];
      #pragma unroll
      for (int pp = 0; pp < 4; ++pp){
        float a0 = fabsf(bf2f((u16)vs[2 * pp])     - bf2f((u16)vd[2 * pp]));
        float a1 = fabsf(bf2f((u16)vs[2 * pp + 1]) - bf2f((u16)vd[2 * pp + 1]));
        pk[pp] = pkbf(a0, a1);
      }
      af[ks].u = make_uint4(pk[0], pk[1], pk[2], pk[3]);
    }
    f32x4 acc[4];
    #pragma unroll
    for (int t = 0; t < 4; ++t) acc[t] = (f32x4){0.f, 0.f, 0.f, 0.f};
    #pragma unroll
    for (int ks = 0; ks < 2; ++ks)
      #pragma unroll
      for (int t = 0; t < 4; ++t)
        acc[t] = __builtin_amdgcn_mfma_f32_16x16x32_bf16(af[ks].v, bfr[t][ks], acc[t], 0, 0, 0);
    #pragma unroll
    for (int r = 0; r < 4; ++r){
      float p = 0.f;
      #pragma unroll
      for (int t = 0; t < 4; ++t)
        p += fmaxf(acc[t][r] + b1v[t], 0.f) * w2v[t];
      #pragma unroll
      for (int mm = 1; mm < 16; mm <<= 1) p += __shfl_xor(p, mm);
      int slot = e0 + q * 4 + r;
      if (m == 0 && slot < E){
        int eid = csrp[slot].z;
        float sc = 1.f / (1.f + __expf(-(p + b2)));
        if (is_f32) ((float*)out)[eid] = sc;
        else        ((u16*)out)[eid]   = f2bf(sc);
      }
    }
  }
}

extern "C" void kernel_launch(void* const* d_in, const int* in_sizes, int n_in,
                              void* d_out, int out_size, void* d_ws, size_t ws_size,
                              hipStream_t stream)
{
  const int* src = (const int*)d_in[1];
  const int* dst = (const int*)d_in[2];

  const int N = in_sizes[0] / 128;
  const int E = in_sizes[1];

  char* p = (char*)d_ws;
  auto alloc = [&](size_t bytes) -> char* {
    char* r = p; p += (bytes + 255) & ~(size_t)255; return r;
  };
  int* flag   = (int*)  alloc(4);
  u16* hc     = (u16*)  alloc((size_t)N * 128 * 2);
  u8*  FT8    = (u8*)   alloc((size_t)N * 256);
  u16* XA     = (u16*)  alloc((size_t)N * 256 * 2);
  u16* XB     = (u16*)  alloc((size_t)N * 256 * 2);
  float* el   = (float*)alloc((size_t)N * 4 * 4);
  float* er   = (float*)alloc((size_t)N * 4 * 4);
  u16* hfb    = (u16*)  alloc((size_t)N * 64 * 2);
  int* rowptr = (int*)  alloc((size_t)(N + 1) * 4);
  int* cursor = (int*)  alloc((size_t)N * 4);
  int* slot   = (int*)  alloc((size_t)E * 4);
  int4* csrp  = (int4*) alloc((size_t)E * 16);
  int* csrs   = (int*)  alloc((size_t)E * 4);
  int* bsums  = (int*)  alloc(1024);
  u16* WT1    = (u16*)  alloc(128 * 256 * 2);
  u16* WTr1   = (u16*)  alloc(128 * 256 * 2);
  u16* WT2    = (u16*)  alloc(256 * 256 * 2);
  u16* WT3    = (u16*)  alloc(256 * 256 * 2);
  u16* al1c   = (u16*)  alloc(256 * 2);
  u16* ar1c   = (u16*)  alloc(256 * 2);
  u16* al2c   = (u16*)  alloc(256 * 2);
  u16* ar2c   = (u16*)  alloc(256 * 2);
  u16* al3c   = (u16*)  alloc(256 * 2);
  u16* ar3c   = (u16*)  alloc(256 * 2);
  u16* Wm1c   = (u16*)  alloc(4096 * 2);
  u16* bm1c   = (u16*)  alloc(64 * 2);
  u16* Wm2c   = (u16*)  alloc(64 * 2);
  u16* bm2c   = (u16*)  alloc(2);

  const int nb = (N + 255) / 256;
  const int ge = (E + 255) / 256;
  const u16* hsrc = (const u16*)d_in[0];

  // flag for edge_mlp's output dtype (nothing else depends on it)
  k_sniff<<<1, 256, 0, stream>>>(hsrc, flag);
  hipMemsetAsync(cursor, 0, (size_t)N * 4, stream);

  // merged prep: canon + LDS transposes + single-atomic-pass CSR positions
  {
    Prep16 t{};
    int b = 0;
    auto put = [&](int idx, const void* s, void* d, void* d2, int n, int K,
                   int mode, int nblk){
      t.e[idx] = {s, d, d2, n, K, mode, b};
      b += nblk;
    };
    put(0,  dst,      slot,  cursor, E,         0,   4, 1024);  // CSR positions
    put(1,  d_in[0],  hc,    nullptr, N * 32,   0,   1, 768);   // h canon (uint2)
    put(2,  d_in[3],  WT1,   nullptr, 0,        128, 2, 32);
    put(3,  d_in[4],  WTr1,  nullptr, 0,        128, 2, 32);
    put(4,  d_in[7],  WT2,   nullptr, 0,        256, 2, 64);
    put(5,  d_in[10], WT3,   nullptr, 0,        256, 2, 64);
    put(6,  d_in[5],  al1c,  nullptr, 256,      0,   0, 1);
    put(7,  d_in[6],  ar1c,  nullptr, 256,      0,   0, 1);
    put(8,  d_in[8],  al2c,  nullptr, 256,      0,   0, 1);
    put(9,  d_in[9],  ar2c,  nullptr, 256,      0,   0, 1);
    put(10, d_in[11], al3c,  nullptr, 256,      0,   0, 1);
    put(11, d_in[12], ar3c,  nullptr, 256,      0,   0, 1);
    put(12, d_in[13], Wm1c,  nullptr, 4096,     0,   0, 1);
    put(13, d_in[14], bm1c,  nullptr, 64,       0,   0, 1);
    put(14, d_in[15], Wm2c,  nullptr, 64,       0,   0, 1);
    put(15, d_in[16], bm2c,  nullptr, 1,        0,   0, 1);
    k_prep<<<dim3(b), 256, 0, stream>>>(t, hsrc);
  }

  // CSR scans + atomic-free placement
  k_scan1<<<nb, 256, 0, stream>>>(cursor, rowptr, bsums, N);
  k_scan2<<<1, 256, 0, stream>>>(bsums, nb);
  k_scan3<<<nb, 256, 0, stream>>>(rowptr, bsums, N);
  k_place<<<512, 256, 0, stream>>>(src, dst, slot, rowptr, csrp, E);
  k_extract<<<ge, 256, 0, stream>>>(csrp, csrs, E);

  const dim3 gA3((N + 127) / 128, 2);
  const dim3 gL1((N + 127) / 128, 2, 2);
  const int gG = (N + 3) / 4;
  const int lds1 = 128 * 128 * 2;   // K=128 B-tile
  const int lds2 = 128 * 256 * 2;   // K=256 B-tile
  // layer 1 (both GEMMs in one launch via grid.z; LDS-staged B)
  mfma_gemm_v4<<<gL1, 256, lds1, stream>>>(hc, WT1, WTr1, FT8, XA, al1c, ar1c, el, er, N, 128);
  aggregate7<<<gG, 256, 0, stream>>>(FT8, el, er, rowptr, csrs, XA, XB, nullptr, 0, N);
  // layer 2
  mfma_gemm_v4<<<gA3, 256, lds2, stream>>>(XB, WT2, WT2, FT8, XA, al2c, ar2c, el, er, N, 256);
  aggregate7<<<gG, 256, 0, stream>>>(FT8, el, er, rowptr, csrs, XB, XA, nullptr, 0, N);
  // layer 3 (fused head-mean -> hf bf16)
  mfma_gemm_v4<<<gA3, 256, lds2, stream>>>(XA, WT3, WT3, FT8, XB, al3c, ar3c, el, er, N, 256);
  aggregate7<<<gG, 256, 0, stream>>>(FT8, el, er, rowptr, csrs, XA, nullptr, hfb, 1, N);
  // edge MLP (MFMA, CSR-ordered for dst-row locality)
  edge_mlp_csr<<<2048, 256, 0, stream>>>(hfb, csrp, Wm1c, bm1c, Wm2c, bm2c,
                                         d_out, E, flag);
}

// Round 3
// 402.503 us; speedup vs baseline: 1.2713x; 1.0428x over previous
//
#include <hip/hip_runtime.h>
#include <hip/hip_bf16.h>

typedef unsigned short u16;
typedef unsigned char u8;
typedef __attribute__((ext_vector_type(8))) short bf16x8;
typedef __attribute__((ext_vector_type(4))) float f32x4;
typedef __attribute__((ext_vector_type(2))) float f32x2;

__device__ __forceinline__ float bf2f(u16 u){
  union { unsigned int i; float f; } v; v.i = ((unsigned int)u) << 16; return v.f;
}
__device__ __forceinline__ u16 f2bf(float f){
  union { float f; unsigned int i; } v; v.f = f;
  unsigned int lsb = (v.i >> 16) & 1u;
  v.i += 0x7fffu + lsb;
  return (u16)(v.i >> 16);
}
__device__ __forceinline__ unsigned pkbf(float a, float b){
  __hip_bfloat162 h = __float22bfloat162_rn(make_float2(a, b));
  union { __hip_bfloat162 h2; unsigned u; } c; c.h2 = h; return c.u;
}
__device__ __forceinline__ u8 f2fp8(float f){
  int p = __builtin_amdgcn_cvt_pk_fp8_f32(f, f, 0, false);
  return (u8)(p & 0xFF);
}

// ---------------- dtype sniffer (flag consumed only by edge_mlp) --------------
__global__ void k_sniff(const u16* __restrict__ p, int* __restrict__ flag){
  __shared__ int s[256];
  int tid = threadIdx.x;
  u16 v = p[2 * tid];
  int e = (v >> 7) & 0xFF;
  s[tid] = (e >= 100 && e <= 135) ? 1 : 0;
  __syncthreads();
  for (int off = 128; off; off >>= 1){
    if (tid < off) s[tid] += s[tid + off];
    __syncthreads();
  }
  if (tid == 0) *flag = (s[0] < 180) ? 1 : 0;
}

// ---------------- merged prep v2: flat work-proportional scheduling -----------
struct PrepEnt { const void* s; void* d; void* d2; int n; int K; int mode; int bstart; };
struct Prep16 { PrepEnt e[16]; };
__global__ void k_prep(Prep16 tab, const u16* __restrict__ hsrc){
  __shared__ int s[256];
  __shared__ u16 tl[32][33];
  {
    int tid = threadIdx.x;
    u16 v = hsrc[2 * tid];
    int e = (v >> 7) & 0xFF;
    s[tid] = (e >= 100 && e <= 135) ? 1 : 0;
    __syncthreads();
    for (int off = 128; off; off >>= 1){
      if (tid < off) s[tid] += s[tid + off];
      __syncthreads();
    }
  }
  const int flag = (s[0] < 180) ? 1 : 0;
  __syncthreads();

  const int bx = blockIdx.x;
  int y = 0;
  #pragma unroll
  for (int i = 1; i < 16; ++i) if (bx >= tab.e[i].bstart) y = i;
  PrepEnt en = tab.e[y];
  const int nblk = ((y < 15) ? tab.e[y + 1].bstart : (int)gridDim.x) - en.bstart;
  const int lb = bx - en.bstart;
  const int T = nblk * 256;
  const int t0 = lb * 256 + threadIdx.x;

  if (en.mode == 1){
    u16* d = (u16*)en.d;
    for (int i = t0; i < en.n; i += T){
      u16 o[4];
      if (flag){
        float4 v = ((const float4*)en.s)[i];
        o[0] = f2bf(v.x); o[1] = f2bf(v.y); o[2] = f2bf(v.z); o[3] = f2bf(v.w);
      } else {
        uint2 v = ((const uint2*)en.s)[i];
        o[0] = (u16)v.x; o[1] = (u16)(v.x >> 16); o[2] = (u16)v.y; o[3] = (u16)(v.y >> 16);
      }
      uint2 w; w.x = o[0] | ((unsigned)o[1] << 16); w.y = o[2] | ((unsigned)o[3] << 16);
      ((uint2*)d)[i] = w;
    }
  } else if (en.mode == 0){
    u16* d = (u16*)en.d;
    for (int i = t0; i < en.n; i += T){
      if (flag) d[i] = f2bf(((const float*)en.s)[i]);
      else      d[i] = ((const u16*)en.s)[i];
    }
  } else if (en.mode == 2){
    // one 32x32 tile per block; coalesced read AND coalesced write
    u16* wt = (u16*)en.d;
    const int K = en.K;
    const int tk = lb >> 3, tc = lb & 7;
    const int tx = threadIdx.x & 31, ty = threadIdx.x >> 5;
    #pragma unroll
    for (int r = 0; r < 4; ++r){
      int row = tk * 32 + ty + r * 8, col = tc * 32 + tx;
      u16 b;
      if (flag) b = f2bf(((const float*)en.s)[row * 256 + col]);
      else      b = ((const u16*)en.s)[row * 256 + col];
      tl[ty + r * 8][tx] = b;
    }
    __syncthreads();
    #pragma unroll
    for (int r = 0; r < 4; ++r){
      int c = tc * 32 + ty + r * 8, k = tk * 32 + tx;
      wt[(size_t)c * K + k] = tl[tx][ty + r * 8];
    }
  } else {
    // mode 4: single atomic pass builds BOTH histogram and scatter positions
    const int* dstp = (const int*)en.s;
    int* slotp = (int*)en.d;
    int* cur   = (int*)en.d2;
    for (int base = t0; base < en.n; base += 4 * T){
      int e0 = base, e1 = base + T, e2 = base + 2 * T, e3 = base + 3 * T;
      bool v0 = e0 < en.n, v1 = e1 < en.n, v2 = e2 < en.n, v3 = e3 < en.n;
      int d0 = 0, d1 = 0, d2 = 0, d3 = 0;
      if (v0) d0 = dstp[e0];
      if (v1) d1 = dstp[e1];
      if (v2) d2 = dstp[e2];
      if (v3) d3 = dstp[e3];
      int p0 = 0, p1 = 0, p2 = 0, p3 = 0;
      if (v0) p0 = atomicAdd(&cur[d0], 1);
      if (v1) p1 = atomicAdd(&cur[d1], 1);
      if (v2) p2 = atomicAdd(&cur[d2], 1);
      if (v3) p3 = atomicAdd(&cur[d3], 1);
      if (v0) slotp[e0] = p0;
      if (v1) slotp[e1] = p1;
      if (v2) slotp[e2] = p2;
      if (v3) slotp[e3] = p3;
    }
  }
}

// ---------------- CSR scans ----------------
__global__ void k_scan1(const int* __restrict__ cnt, int* __restrict__ rowptr,
                        int* __restrict__ bsums, int N){
  __shared__ int s[256];
  int i = blockIdx.x * 256 + threadIdx.x;
  int v = (i < N) ? cnt[i] : 0;
  s[threadIdx.x] = v; __syncthreads();
  for (int off = 1; off < 256; off <<= 1){
    int x = 0;
    if (threadIdx.x >= off) x = s[threadIdx.x - off];
    __syncthreads();
    s[threadIdx.x] += x;
    __syncthreads();
  }
  if (i < N) rowptr[i + 1] = s[threadIdx.x];
  if (threadIdx.x == 255) bsums[blockIdx.x] = s[255];
}
__global__ void k_scan2(int* __restrict__ bsums, int nb){
  __shared__ int s[256];
  int t = threadIdx.x;
  int v = (t < nb) ? bsums[t] : 0;
  s[t] = v; __syncthreads();
  for (int off = 1; off < 256; off <<= 1){
    int x = 0;
    if (t >= off) x = s[t - off];
    __syncthreads();
    s[t] += x;
    __syncthreads();
  }
  if (t < nb) bsums[t] = s[t] - v;                // exclusive
}
__global__ void k_scan3(int* __restrict__ rowptr, const int* __restrict__ bsums, int N){
  int i = blockIdx.x * 256 + threadIdx.x;
  if (i < N){
    rowptr[i + 1] += bsums[blockIdx.x];
    if (i == 0) rowptr[0] = 0;
  }
}
// atomic-free CSR placement using precomputed slots
__global__ void k_place(const int* __restrict__ src, const int* __restrict__ dst,
                        const int* __restrict__ slot, const int* __restrict__ rowptr,
                        int4* __restrict__ csrp, int E){
  const int T = gridDim.x * 256;
  for (int i = blockIdx.x * 256 + threadIdx.x; i < E; i += T){
    int d = dst[i];
    csrp[rowptr[d] + slot[i]] = make_int4(src[i], d, i, 0);
  }
}
// coalesced src-extraction: csrs[i] = csrp[i].x
__global__ void k_extract(const int4* __restrict__ csrp, int* __restrict__ csrs, int E){
  int i = blockIdx.x * 256 + threadIdx.x;
  if (i < E) csrs[i] = csrp[i].x;
}

// ---------------- unified LDS-staged GEMM (v4) --------------------------------
__global__ __launch_bounds__(256, 4) void mfma_gemm_v4(
    const u16* __restrict__ X, const u16* __restrict__ WT, const u16* __restrict__ WTr,
    u8* __restrict__ FT8, u16* __restrict__ XA,
    const u16* __restrict__ al, const u16* __restrict__ ar,
    float* __restrict__ el4, float* __restrict__ er4, int N, int K)
{
  extern __shared__ u16 Bs[];                 // 128 * K * 2 bytes (32/64 KB)
  const int wv = threadIdx.x >> 6;
  const int lane = threadIdx.x & 63;
  const int m = lane & 15;
  const int q = lane >> 4;
  const int row0 = blockIdx.x * 128 + wv * 32;
  const int col0 = blockIdx.y * 128;
  const u16* W = (blockIdx.z == 0) ? WT : WTr;

  // ---- stage B into LDS (linear dest, pre-swizzled global source) ----
  {
    const int spr = K >> 3;                   // 16B slots per row (16 or 32)
    const int ish = (spr == 32) ? 5 : 4;
    const int nIss = K >> 4;                  // issues per thread (8 or 16)
    for (int j = 0; j < nIss; ++j){
      int cbase = (j * 4 + wv) * 64;          // wave-uniform chunk base
      int chunk = cbase + lane;
      int col = chunk >> ish;
      int slot = chunk & (spr - 1);
      int gslot = slot ^ (col & 7);
      const u16* srcp = W + (size_t)(col0 + col) * K + gslot * 8;
      u16* dstp = Bs + (size_t)cbase * 8;     // wave-uniform; HW adds lane*16
      __builtin_amdgcn_global_load_lds((const unsigned int*)srcp,
                                       (unsigned int*)dstp, 16, 0, 0);
    }
  }

  f32x4 acc[2][8];
  #pragma unroll
  for (int g = 0; g < 2; ++g)
    #pragma unroll
    for (int t = 0; t < 8; ++t) acc[g][t] = (f32x4){0.f, 0.f, 0.f, 0.f};
  const int rA = row0 + m, rB = row0 + 16 + m;
  const bool vA = rA < N, vB = rB < N;
  const u16* apA = X + (size_t)rA * K + q * 8;
  const u16* apB = X + (size_t)rB * K + q * 8;

  asm volatile("s_waitcnt vmcnt(0)" ::: "memory");
  __syncthreads();

  const int mh = m & 7;
  // barrier-free main loop: B via ds_read_b128, A streamed from global
  for (int k0 = 0; k0 < K; k0 += 32){
    bf16x8 aA = {}, aB = {};
    if (vA) aA = *(const bf16x8*)(apA + k0);
    if (vB) aB = *(const bf16x8*)(apB + k0);
    const int sb = (k0 >> 3) + q;             // linear slot for this lane
    #pragma unroll
    for (int t = 0; t < 8; ++t){
      const u16* bp = Bs + (size_t)(t * 16 + m) * K + (size_t)(sb ^ mh) * 8;
      bf16x8 b = *(const bf16x8*)bp;
      acc[0][t] = __builtin_amdgcn_mfma_f32_16x16x32_bf16(aA, b, acc[0][t], 0, 0, 0);
      acc[1][t] = __builtin_amdgcn_mfma_f32_16x16x32_bf16(aB, b, acc[1][t], 0, 0, 0);
    }
  }

  if (blockIdx.z == 0){
    float alv[8], arv[8];
    #pragma unroll
    for (int t = 0; t < 8; ++t){
      alv[t] = bf2f(al[col0 + t * 16 + m]);
      arv[t] = bf2f(ar[col0 + t * 16 + m]);
    }
    #pragma unroll
    for (int g = 0; g < 2; ++g)
      #pragma unroll
      for (int r = 0; r < 4; ++r){
        float pe[2] = {0.f, 0.f}, pr[2] = {0.f, 0.f};
        #pragma unroll
        for (int t = 0; t < 8; ++t){
          pe[t >> 2] += acc[g][t][r] * alv[t];
          pr[t >> 2] += acc[g][t][r] * arv[t];
        }
        #pragma unroll
        for (int mk = 1; mk < 16; mk <<= 1){
          pe[0] += __shfl_xor(pe[0], mk); pe[1] += __shfl_xor(pe[1], mk);
          pr[0] += __shfl_xor(pr[0], mk); pr[1] += __shfl_xor(pr[1], mk);
        }
        int rr = row0 + g * 16 + q * 4 + r;
        if (m == 0 && rr < N){
          *(float2*)(el4 + (size_t)rr * 4 + blockIdx.y * 2) = make_float2(pe[0], pe[1]);
          *(float2*)(er4 + (size_t)rr * 4 + blockIdx.y * 2) = make_float2(pr[0], pr[1]);
        }
      }
    #pragma unroll
    for (int g = 0; g < 2; ++g)
      #pragma unroll
      for (int t = 0; t < 8; ++t){
        int col = col0 + t * 16 + m;
        #pragma unroll
        for (int r = 0; r < 4; ++r){
          int rr = row0 + g * 16 + q * 4 + r;
          if (rr < N) FT8[(size_t)rr * 256 + col] = f2fp8(acc[g][t][r]);
        }
      }
  } else {
    #pragma unroll
    for (int g = 0; g < 2; ++g)
      #pragma unroll
      for (int t = 0; t < 8; ++t){
        int col = col0 + t * 16 + m;
        #pragma unroll
        for (int r = 0; r < 4; ++r){
          int rr = row0 + g * 16 + q * 4 + r;
          if (rr < N) XA[(size_t)rr * 256 + col] = f2bf(acc[g][t][r]);
        }
      }
  }
}

// ---------------- aggregation v8: 4 dsts/wave, single-pass deferred norm ------
// lane = g*16 + t : group g owns dst (blk*16 + w*4 + g), lane t covers cols
// t*16..t*16+15 (all within head t>>2). Weights accumulated unnormalized;
// scaled by 1/den in the epilogue (same weights as softmax, different assoc).
__global__ __launch_bounds__(256) void aggregate8(
    const u8* __restrict__ ft8, const float* __restrict__ el4, const float* __restrict__ er4,
    const int* __restrict__ rowptr, const int* __restrict__ csrs,
    const u16* __restrict__ residb, u16* __restrict__ outb,
    u16* __restrict__ hf, int do_hf, int N)
{
  __shared__ float sal[4][4][17][4];   // [wave][group][edge(+pad)][head]
  __shared__ int   sof[4][4][16];
  const int w = threadIdx.x >> 6, lane = threadIdx.x & 63;
  const int g = lane >> 4, t = lane & 15;
  const int hd = t >> 2;
  const int d = blockIdx.x * 16 + w * 4 + g;
  const bool vd = d < N;
  int beg = 0, deg = 0;
  if (vd){ beg = rowptr[d]; deg = rowptr[d + 1] - beg; }
  int mdeg = deg;
  mdeg = max(mdeg, __shfl_xor(mdeg, 16));
  mdeg = max(mdeg, __shfl_xor(mdeg, 32));
  float4 erd = make_float4(0.f, 0.f, 0.f, 0.f);
  if (vd) erd = ((const float4*)er4)[d];

  f32x2 acc2[8];
  #pragma unroll
  for (int i = 0; i < 8; ++i) acc2[i] = (f32x2){0.f, 0.f};
  float den[4] = {0.f, 0.f, 0.f, 0.f};

  for (int c0 = 0; c0 < mdeg; c0 += 16){
    const int rem = deg - c0;                 // may be <=0 for this group
    // ---- phase A: one edge per lane; raw exp weights + den accumulate ----
    float t0 = 0.f, t1 = 0.f, t2 = 0.f, t3 = 0.f; int s = 0;
    if (t < rem){
      s = csrs[beg + c0 + t];
      float4 ql = ((const float4*)el4)[s];
      float e0 = ql.x + erd.x; e0 = (e0 > 0.f) ? e0 : 0.2f * e0;
      float e1 = ql.y + erd.y; e1 = (e1 > 0.f) ? e1 : 0.2f * e1;
      float e2 = ql.z + erd.z; e2 = (e2 > 0.f) ? e2 : 0.2f * e2;
      float e3 = ql.w + erd.w; e3 = (e3 > 0.f) ? e3 : 0.2f * e3;
      t0 = __expf(fminf(e0, 60.f)); t1 = __expf(fminf(e1, 60.f));
      t2 = __expf(fminf(e2, 60.f)); t3 = __expf(fminf(e3, 60.f));
    }
    den[0] += t0; den[1] += t1; den[2] += t2; den[3] += t3;
    sal[w][g][t][0] = t0; sal[w][g][t][1] = t1;
    sal[w][g][t][2] = t2; sal[w][g][t][3] = t3;
    sof[w][g][t] = s << 8;                    // byte offset of fp8 row
    __builtin_amdgcn_wave_barrier();
    // ---- phase B: 4 edges/iter, 4 gathers in flight ----
    int cr = rem < 16 ? (rem < 0 ? 0 : rem) : 16;
    int jm = (cr + 3) & ~3;
    for (int j = 0; j < jm; j += 4){
      float a[4]; unsigned off[4]; uint4 v[4];
      #pragma unroll
      for (int u = 0; u < 4; ++u){
        a[u] = sal[w][g][j + u][hd];
        off[u] = (unsigned)sof[w][g][j + u];
      }
      #pragma unroll
      for (int u = 0; u < 4; ++u)
        v[u] = *(const uint4*)(ft8 + (size_t)off[u] + t * 16);
      #pragma unroll
      for (int u = 0; u < 4; ++u){
        f32x2 a2 = (f32x2){a[u], a[u]};
        acc2[0] += __builtin_amdgcn_cvt_pk_f32_fp8(v[u].x, 0) * a2;
        acc2[1] += __builtin_amdgcn_cvt_pk_f32_fp8(v[u].x, 1) * a2;
        acc2[2] += __builtin_amdgcn_cvt_pk_f32_fp8(v[u].y, 0) * a2;
        acc2[3] += __builtin_amdgcn_cvt_pk_f32_fp8(v[u].y, 1) * a2;
        acc2[4] += __builtin_amdgcn_cvt_pk_f32_fp8(v[u].z, 0) * a2;
        acc2[5] += __builtin_amdgcn_cvt_pk_f32_fp8(v[u].z, 1) * a2;
        acc2[6] += __builtin_amdgcn_cvt_pk_f32_fp8(v[u].w, 0) * a2;
        acc2[7] += __builtin_amdgcn_cvt_pk_f32_fp8(v[u].w, 1) * a2;
      }
    }
    __builtin_amdgcn_wave_barrier();
  }
  // den reduce within 16-lane group (xor 1,2,4,8 stays in-group)
  #pragma unroll
  for (int mk = 1; mk < 16; mk <<= 1){
    den[0] += __shfl_xor(den[0], mk); den[1] += __shfl_xor(den[1], mk);
    den[2] += __shfl_xor(den[2], mk); den[3] += __shfl_xor(den[3], mk);
  }
  const float dh = den[hd];
  const float inv = (dh > 0.f) ? (1.f / dh) : 0.f;

  if (!vd) return;
  // resid: 16 bf16 = 32B per lane
  const u16* rp = residb + (size_t)d * 256 + t * 16;
  uint4 r0 = *(const uint4*)rp;
  uint4 r1 = *(const uint4*)(rp + 8);
  float o[16];
  {
    union { unsigned u; float f; } x;
    unsigned rw[8] = {r0.x, r0.y, r0.z, r0.w, r1.x, r1.y, r1.z, r1.w};
    #pragma unroll
    for (int i = 0; i < 8; ++i){
      x.u = rw[i] << 16;          o[2 * i]     = x.f;
      x.u = rw[i] & 0xffff0000u;  o[2 * i + 1] = x.f;
    }
  }
  #pragma unroll
  for (int i = 0; i < 8; ++i){
    o[2 * i]     += acc2[i].x * inv;
    o[2 * i + 1] += acc2[i].y * inv;
  }
  if (!do_hf){
    uint4 a, b;
    a.x = pkbf(fmaxf(o[0], 0.f),  fmaxf(o[1], 0.f));
    a.y = pkbf(fmaxf(o[2], 0.f),  fmaxf(o[3], 0.f));
    a.z = pkbf(fmaxf(o[4], 0.f),  fmaxf(o[5], 0.f));
    a.w = pkbf(fmaxf(o[6], 0.f),  fmaxf(o[7], 0.f));
    b.x = pkbf(fmaxf(o[8], 0.f),  fmaxf(o[9], 0.f));
    b.y = pkbf(fmaxf(o[10], 0.f), fmaxf(o[11], 0.f));
    b.z = pkbf(fmaxf(o[12], 0.f), fmaxf(o[13], 0.f));
    b.w = pkbf(fmaxf(o[14], 0.f), fmaxf(o[15], 0.f));
    u16* op = outb + (size_t)d * 256 + t * 16;
    *(uint4*)op = a;
    *(uint4*)(op + 8) = b;
  } else {
    // head-mean: cols k,k+64,k+128,k+192 live at lanes t0,t0+4,t0+8,t0+12
    #pragma unroll
    for (int i = 0; i < 16; ++i){
      float v = o[i];
      v += __shfl_xor(v, 4);
      v += __shfl_xor(v, 8);
      o[i] = 0.25f * v;
    }
    if (t < 4){
      uint4 a, b;
      a.x = pkbf(o[0], o[1]);   a.y = pkbf(o[2], o[3]);
      a.z = pkbf(o[4], o[5]);   a.w = pkbf(o[6], o[7]);
      b.x = pkbf(o[8], o[9]);   b.y = pkbf(o[10], o[11]);
      b.z = pkbf(o[12], o[13]); b.w = pkbf(o[14], o[15]);
      u16* hp = hf + (size_t)d * 64 + t * 16;
      *(uint4*)hp = a;
      *(uint4*)(hp + 8) = b;
    }
  }
}

// ---------------- MFMA edge MLP, CSR-ordered ----------------------------------
__global__ __launch_bounds__(256) void edge_mlp_csr(
    const u16* __restrict__ hfb, const int4* __restrict__ csrp,
    const u16* __restrict__ Wm1, const u16* __restrict__ bm1,
    const u16* __restrict__ Wm2, const u16* __restrict__ bm2,
    void* __restrict__ out, int E, const int* __restrict__ flag)
{
  const int lane = threadIdx.x & 63;
  const int m = lane & 15;
  const int q = lane >> 4;
  const int is_f32 = *flag;

  bf16x8 bfr[4][2];
  #pragma unroll
  for (int t = 0; t < 4; ++t)
    #pragma unroll
    for (int ks = 0; ks < 2; ++ks)
      #pragma unroll
      for (int j = 0; j < 8; ++j)
        bfr[t][ks][j] = (short)Wm1[(size_t)(ks * 32 + q * 8 + j) * 64 + t * 16 + m];

  float b1v[4], w2v[4];
  #pragma unroll
  for (int t = 0; t < 4; ++t){
    b1v[t] = bf2f(bm1[t * 16 + m]);
    w2v[t] = bf2f(Wm2[t * 16 + m]);
  }
  const float b2 = bf2f(bm2[0]);

  const int wid = blockIdx.x * 4 + (threadIdx.x >> 6);
  const int nw  = gridDim.x * 4;
  for (int e0 = wid * 16; e0 < E; e0 += nw * 16){
    int e = e0 + m; if (e >= E) e = E - 1;
    int4 ed = csrp[e];
    const u16* ps = hfb + (size_t)ed.x * 64;
    const u16* pd = hfb + (size_t)ed.y * 64;
    union { bf16x8 v; uint4 u; } af[2];
    #pragma unroll
    for (int ks = 0; ks < 2; ++ks){
      bf16x8 vs = *(const bf16x8*)(ps + ks * 32 + q * 8);
      bf16x8 vd = *(const bf16x8*)(pd + ks * 32 + q * 8);
      unsigned pk[4];
      #pragma unroll
      for (int pp = 0; pp < 4; ++pp){
        float a0 = fabsf(bf2f((u16)vs[2 * pp])     - bf2f((u16)vd[2 * pp]));
        float a1 = fabsf(bf2f((u16)vs[2 * pp + 1]) - bf2f((u16)vd[2 * pp + 1]));
        pk[pp] = pkbf(a0, a1);
      }
      af[ks].u = make_uint4(pk[0], pk[1], pk[2], pk[3]);
    }
    f32x4 acc[4];
    #pragma unroll
    for (int t = 0; t < 4; ++t) acc[t] = (f32x4){0.f, 0.f, 0.f, 0.f};
    #pragma unroll
    for (int ks = 0; ks < 2; ++ks)
      #pragma unroll
      for (int t = 0; t < 4; ++t)
        acc[t] = __builtin_amdgcn_mfma_f32_16x16x32_bf16(af[ks].v, bfr[t][ks], acc[t], 0, 0, 0);
    #pragma unroll
    for (int r = 0; r < 4; ++r){
      float p = 0.f;
      #pragma unroll
      for (int t = 0; t < 4; ++t)
        p += fmaxf(acc[t][r] + b1v[t], 0.f) * w2v[t];
      #pragma unroll
      for (int mm = 1; mm < 16; mm <<= 1) p += __shfl_xor(p, mm);
      int slot = e0 + q * 4 + r;
      if (m == 0 && slot < E){
        int eid = csrp[slot].z;
        float sc = 1.f / (1.f + __expf(-(p + b2)));
        if (is_f32) ((float*)out)[eid] = sc;
        else        ((u16*)out)[eid]   = f2bf(sc);
      }
    }
  }
}

extern "C" void kernel_launch(void* const* d_in, const int* in_sizes, int n_in,
                              void* d_out, int out_size, void* d_ws, size_t ws_size,
                              hipStream_t stream)
{
  const int* src = (const int*)d_in[1];
  const int* dst = (const int*)d_in[2];

  const int N = in_sizes[0] / 128;
  const int E = in_sizes[1];

  char* p = (char*)d_ws;
  auto alloc = [&](size_t bytes) -> char* {
    char* r = p; p += (bytes + 255) & ~(size_t)255; return r;
  };
  int* flag   = (int*)  alloc(4);
  u16* hc     = (u16*)  alloc((size_t)N * 128 * 2);
  u8*  FT8    = (u8*)   alloc((size_t)N * 256);
  u16* XA     = (u16*)  alloc((size_t)N * 256 * 2);
  u16* XB     = (u16*)  alloc((size_t)N * 256 * 2);
  float* el   = (float*)alloc((size_t)N * 4 * 4);
  float* er   = (float*)alloc((size_t)N * 4 * 4);
  u16* hfb    = (u16*)  alloc((size_t)N * 64 * 2);
  int* rowptr = (int*)  alloc((size_t)(N + 1) * 4);
  int* cursor = (int*)  alloc((size_t)N * 4);
  int* slot   = (int*)  alloc((size_t)E * 4);
  int4* csrp  = (int4*) alloc((size_t)E * 16);
  int* csrs   = (int*)  alloc((size_t)E * 4);
  int* bsums  = (int*)  alloc(1024);
  u16* WT1    = (u16*)  alloc(128 * 256 * 2);
  u16* WTr1   = (u16*)  alloc(128 * 256 * 2);
  u16* WT2    = (u16*)  alloc(256 * 256 * 2);
  u16* WT3    = (u16*)  alloc(256 * 256 * 2);
  u16* al1c   = (u16*)  alloc(256 * 2);
  u16* ar1c   = (u16*)  alloc(256 * 2);
  u16* al2c   = (u16*)  alloc(256 * 2);
  u16* ar2c   = (u16*)  alloc(256 * 2);
  u16* al3c   = (u16*)  alloc(256 * 2);
  u16* ar3c   = (u16*)  alloc(256 * 2);
  u16* Wm1c   = (u16*)  alloc(4096 * 2);
  u16* bm1c   = (u16*)  alloc(64 * 2);
  u16* Wm2c   = (u16*)  alloc(64 * 2);
  u16* bm2c   = (u16*)  alloc(2);

  const int nb = (N + 255) / 256;
  const int ge = (E + 255) / 256;
  const u16* hsrc = (const u16*)d_in[0];

  // flag for edge_mlp's output dtype (nothing else depends on it)
  k_sniff<<<1, 256, 0, stream>>>(hsrc, flag);
  hipMemsetAsync(cursor, 0, (size_t)N * 4, stream);

  // merged prep: canon + LDS transposes + single-atomic-pass CSR positions
  {
    Prep16 t{};
    int b = 0;
    auto put = [&](int idx, const void* s, void* d, void* d2, int n, int K,
                   int mode, int nblk){
      t.e[idx] = {s, d, d2, n, K, mode, b};
      b += nblk;
    };
    put(0,  dst,      slot,  cursor, E,         0,   4, 1024);  // CSR positions
    put(1,  d_in[0],  hc,    nullptr, N * 32,   0,   1, 768);   // h canon (uint2)
    put(2,  d_in[3],  WT1,   nullptr, 0,        128, 2, 32);
    put(3,  d_in[4],  WTr1,  nullptr, 0,        128, 2, 32);
    put(4,  d_in[7],  WT2,   nullptr, 0,        256, 2, 64);
    put(5,  d_in[10], WT3,   nullptr, 0,        256, 2, 64);
    put(6,  d_in[5],  al1c,  nullptr, 256,      0,   0, 1);
    put(7,  d_in[6],  ar1c,  nullptr, 256,      0,   0, 1);
    put(8,  d_in[8],  al2c,  nullptr, 256,      0,   0, 1);
    put(9,  d_in[9],  ar2c,  nullptr, 256,      0,   0, 1);
    put(10, d_in[11], al3c,  nullptr, 256,      0,   0, 1);
    put(11, d_in[12], ar3c,  nullptr, 256,      0,   0, 1);
    put(12, d_in[13], Wm1c,  nullptr, 4096,     0,   0, 1);
    put(13, d_in[14], bm1c,  nullptr, 64,       0,   0, 1);
    put(14, d_in[15], Wm2c,  nullptr, 64,       0,   0, 1);
    put(15, d_in[16], bm2c,  nullptr, 1,        0,   0, 1);
    k_prep<<<dim3(b), 256, 0, stream>>>(t, hsrc);
  }

  // CSR scans + atomic-free placement
  k_scan1<<<nb, 256, 0, stream>>>(cursor, rowptr, bsums, N);
  k_scan2<<<1, 256, 0, stream>>>(bsums, nb);
  k_scan3<<<nb, 256, 0, stream>>>(rowptr, bsums, N);
  k_place<<<512, 256, 0, stream>>>(src, dst, slot, rowptr, csrp, E);
  k_extract<<<ge, 256, 0, stream>>>(csrp, csrs, E);

  const dim3 gA3((N + 127) / 128, 2);
  const dim3 gL1((N + 127) / 128, 2, 2);
  const int gG = (N + 15) / 16;
  const int lds1 = 128 * 128 * 2;   // K=128 B-tile
  const int lds2 = 128 * 256 * 2;   // K=256 B-tile
  // layer 1 (both GEMMs in one launch via grid.z; LDS-staged B)
  mfma_gemm_v4<<<gL1, 256, lds1, stream>>>(hc, WT1, WTr1, FT8, XA, al1c, ar1c, el, er, N, 128);
  aggregate8<<<gG, 256, 0, stream>>>(FT8, el, er, rowptr, csrs, XA, XB, nullptr, 0, N);
  // layer 2
  mfma_gemm_v4<<<gA3, 256, lds2, stream>>>(XB, WT2, WT2, FT8, XA, al2c, ar2c, el, er, N, 256);
  aggregate8<<<gG, 256, 0, stream>>>(FT8, el, er, rowptr, csrs, XB, XA, nullptr, 0, N);
  // layer 3 (fused head-mean -> hf bf16)
  mfma_gemm_v4<<<gA3, 256, lds2, stream>>>(XA, WT3, WT3, FT8, XB, al3c, ar3c, el, er, N, 256);
  aggregate8<<<gG, 256, 0, stream>>>(FT8, el, er, rowptr, csrs, XA, nullptr, hfb, 1, N);
  // edge MLP (MFMA, CSR-ordered for dst-row locality)
  edge_mlp_csr<<<2048, 256, 0, stream>>>(hfb, csrp, Wm1c, bm1c, Wm2c, bm2c,
                                         d_out, E, flag);
}

// Round 4
// 394.814 us; speedup vs baseline: 1.2961x; 1.0195x over previous
//
#include <hip/hip_runtime.h>
#include <hip/hip_bf16.h>

typedef unsigned short u16;
typedef unsigned char u8;
typedef __attribute__((ext_vector_type(8))) short bf16x8;
typedef __attribute__((ext_vector_type(4))) float f32x4;
typedef __attribute__((ext_vector_type(2))) float f32x2;

__device__ __forceinline__ float bf2f(u16 u){
  union { unsigned int i; float f; } v; v.i = ((unsigned int)u) << 16; return v.f;
}
__device__ __forceinline__ u16 f2bf(float f){
  union { float f; unsigned int i; } v; v.f = f;
  unsigned int lsb = (v.i >> 16) & 1u;
  v.i += 0x7fffu + lsb;
  return (u16)(v.i >> 16);
}
__device__ __forceinline__ unsigned pkbf(float a, float b){
  __hip_bfloat162 h = __float22bfloat162_rn(make_float2(a, b));
  union { __hip_bfloat162 h2; unsigned u; } c; c.h2 = h; return c.u;
}
__device__ __forceinline__ u8 f2fp8(float f){
  int p = __builtin_amdgcn_cvt_pk_fp8_f32(f, f, 0, false);
  return (u8)(p & 0xFF);
}

// ---------------- dtype sniffer (flag consumed only by edge_mlp) --------------
__global__ void k_sniff(const u16* __restrict__ p, int* __restrict__ flag){
  __shared__ int s[256];
  int tid = threadIdx.x;
  u16 v = p[2 * tid];
  int e = (v >> 7) & 0xFF;
  s[tid] = (e >= 100 && e <= 135) ? 1 : 0;
  __syncthreads();
  for (int off = 128; off; off >>= 1){
    if (tid < off) s[tid] += s[tid + off];
    __syncthreads();
  }
  if (tid == 0) *flag = (s[0] < 180) ? 1 : 0;
}

// ---------------- merged prep v3: canon + transposes only ---------------------
struct PrepEnt { const void* s; void* d; void* d2; int n; int K; int mode; int bstart; };
struct Prep16 { PrepEnt e[16]; };
__global__ void k_prep(Prep16 tab, const u16* __restrict__ hsrc){
  __shared__ int s[256];
  __shared__ u16 tl[32][33];
  {
    int tid = threadIdx.x;
    u16 v = hsrc[2 * tid];
    int e = (v >> 7) & 0xFF;
    s[tid] = (e >= 100 && e <= 135) ? 1 : 0;
    __syncthreads();
    for (int off = 128; off; off >>= 1){
      if (tid < off) s[tid] += s[tid + off];
      __syncthreads();
    }
  }
  const int flag = (s[0] < 180) ? 1 : 0;
  __syncthreads();

  const int bx = blockIdx.x;
  int y = 0;
  #pragma unroll
  for (int i = 1; i < 16; ++i) if (bx >= tab.e[i].bstart) y = i;
  PrepEnt en = tab.e[y];
  const int nblk = ((y < 15) ? tab.e[y + 1].bstart : (int)gridDim.x) - en.bstart;
  const int lb = bx - en.bstart;
  const int T = nblk * 256;
  const int t0 = lb * 256 + threadIdx.x;

  if (en.mode == 1){
    u16* d = (u16*)en.d;
    for (int i = t0; i < en.n; i += T){
      u16 o[4];
      if (flag){
        float4 v = ((const float4*)en.s)[i];
        o[0] = f2bf(v.x); o[1] = f2bf(v.y); o[2] = f2bf(v.z); o[3] = f2bf(v.w);
      } else {
        uint2 v = ((const uint2*)en.s)[i];
        o[0] = (u16)v.x; o[1] = (u16)(v.x >> 16); o[2] = (u16)v.y; o[3] = (u16)(v.y >> 16);
      }
      uint2 w; w.x = o[0] | ((unsigned)o[1] << 16); w.y = o[2] | ((unsigned)o[3] << 16);
      ((uint2*)d)[i] = w;
    }
  } else if (en.mode == 0){
    u16* d = (u16*)en.d;
    for (int i = t0; i < en.n; i += T){
      if (flag) d[i] = f2bf(((const float*)en.s)[i]);
      else      d[i] = ((const u16*)en.s)[i];
    }
  } else if (en.mode == 2){
    // one 32x32 tile per block; coalesced read AND coalesced write
    u16* wt = (u16*)en.d;
    const int K = en.K;
    const int tk = lb >> 3, tc = lb & 7;
    const int tx = threadIdx.x & 31, ty = threadIdx.x >> 5;
    #pragma unroll
    for (int r = 0; r < 4; ++r){
      int row = tk * 32 + ty + r * 8, col = tc * 32 + tx;
      u16 b;
      if (flag) b = f2bf(((const float*)en.s)[row * 256 + col]);
      else      b = ((const u16*)en.s)[row * 256 + col];
      tl[ty + r * 8][tx] = b;
    }
    __syncthreads();
    #pragma unroll
    for (int r = 0; r < 4; ++r){
      int c = tc * 32 + ty + r * 8, k = tk * 32 + tx;
      wt[(size_t)c * K + k] = tl[tx][ty + r * 8];
    }
  }
}

// ---------------- CSR scans (4-replica counters) ----------------
__global__ void k_scan1(int4* __restrict__ cnt4, int* __restrict__ rowptr,
                        int* __restrict__ bsums, int N){
  __shared__ int s[256];
  int i = blockIdx.x * 256 + threadIdx.x;
  int4 c = make_int4(0, 0, 0, 0);
  if (i < N) c = cnt4[i];
  int v = c.x + c.y + c.z + c.w;
  if (i < N) cnt4[i] = make_int4(0, c.x, c.x + c.y, c.x + c.y + c.z); // excl bases
  s[threadIdx.x] = v; __syncthreads();
  for (int off = 1; off < 256; off <<= 1){
    int x = 0;
    if (threadIdx.x >= off) x = s[threadIdx.x - off];
    __syncthreads();
    s[threadIdx.x] += x;
    __syncthreads();
  }
  if (i < N) rowptr[i + 1] = s[threadIdx.x];
  if (threadIdx.x == 255) bsums[blockIdx.x] = s[255];
}
__global__ void k_scan2(int* __restrict__ bsums, int nb){
  __shared__ int s[256];
  int t = threadIdx.x;
  int v = (t < nb) ? bsums[t] : 0;
  s[t] = v; __syncthreads();
  for (int off = 1; off < 256; off <<= 1){
    int x = 0;
    if (t >= off) x = s[t - off];
    __syncthreads();
    s[t] += x;
    __syncthreads();
  }
  if (t < nb) bsums[t] = s[t] - v;                // exclusive
}
__global__ void k_scan3(int* __restrict__ rowptr, const int* __restrict__ bsums, int N){
  int i = blockIdx.x * 256 + threadIdx.x;
  if (i < N){
    rowptr[i + 1] += bsums[blockIdx.x];
    if (i == 0) rowptr[0] = 0;
  }
}
// atomic-free CSR placement using precomputed slots + replica bases
__global__ void k_place(const int* __restrict__ src, const int* __restrict__ dst,
                        const int* __restrict__ slot, const int* __restrict__ rowptr,
                        const int* __restrict__ cur4, int4* __restrict__ csrp, int E){
  const int T = gridDim.x * 256;
  for (int i = blockIdx.x * 256 + threadIdx.x; i < E; i += T){
    int d = dst[i];
    int base = cur4[(d << 2) | (i & 3)];
    csrp[rowptr[d] + base + slot[i]] = make_int4(src[i], d, i, 0);
  }
}
// coalesced src-extraction: csrs[i] = csrp[i].x
__global__ void k_extract(const int4* __restrict__ csrp, int* __restrict__ csrs, int E){
  int i = blockIdx.x * 256 + threadIdx.x;
  if (i < E) csrs[i] = csrp[i].x;
}

// ---------------- unified LDS-staged GEMM (v5) + fused CSR position pass ------
// do_csr!=0 (layer-1 launch, grid (x,2,2)): each block additionally processes
// ~512 edges of the CSR position pass: slot[e] = atomicAdd(&cur4[dst*4+(e&3)],1).
// Atomics issued right after the MFMA loop (no further A-loads -> no vmcnt
// poisoning of the main loop); results consumed at kernel end.
__global__ __launch_bounds__(256, 4) void mfma_gemm_v5(
    const u16* __restrict__ X, const u16* __restrict__ WT, const u16* __restrict__ WTr,
    u8* __restrict__ FT8, u16* __restrict__ XA,
    const u16* __restrict__ al, const u16* __restrict__ ar,
    float* __restrict__ el4, float* __restrict__ er4, int N, int K,
    const int* __restrict__ edst, int* __restrict__ slotp, int* __restrict__ cur4,
    int Etot, int do_csr)
{
  extern __shared__ u16 Bs[];                 // 128 * K * 2 bytes (32/64 KB)
  const int wv = threadIdx.x >> 6;
  const int lane = threadIdx.x & 63;
  const int m = lane & 15;
  const int q = lane >> 4;
  const int row0 = blockIdx.x * 128 + wv * 32;
  const int col0 = blockIdx.y * 128;
  const u16* W = (blockIdx.z == 0) ? WT : WTr;

  // ---- stage B into LDS (linear dest, pre-swizzled global source) ----
  {
    const int spr = K >> 3;                   // 16B slots per row (16 or 32)
    const int ish = (spr == 32) ? 5 : 4;
    const int nIss = K >> 4;                  // issues per thread (8 or 16)
    for (int j = 0; j < nIss; ++j){
      int cbase = (j * 4 + wv) * 64;          // wave-uniform chunk base
      int chunk = cbase + lane;
      int col = chunk >> ish;
      int slot = chunk & (spr - 1);
      int gslot = slot ^ (col & 7);
      const u16* srcp = W + (size_t)(col0 + col) * K + gslot * 8;
      u16* dstp = Bs + (size_t)cbase * 8;     // wave-uniform; HW adds lane*16
      __builtin_amdgcn_global_load_lds((const unsigned int*)srcp,
                                       (unsigned int*)dstp, 16, 0, 0);
    }
  }

  f32x4 acc[2][8];
  #pragma unroll
  for (int g = 0; g < 2; ++g)
    #pragma unroll
    for (int t = 0; t < 8; ++t) acc[g][t] = (f32x4){0.f, 0.f, 0.f, 0.f};
  const int rA = row0 + m, rB = row0 + 16 + m;
  const bool vA = rA < N, vB = rB < N;
  const u16* apA = X + (size_t)rA * K + q * 8;
  const u16* apB = X + (size_t)rB * K + q * 8;

  asm volatile("s_waitcnt vmcnt(0)" ::: "memory");
  __syncthreads();

  const int mh = m & 7;
  // barrier-free main loop: B via ds_read_b128, A streamed from global
  for (int k0 = 0; k0 < K; k0 += 32){
    bf16x8 aA = {}, aB = {};
    if (vA) aA = *(const bf16x8*)(apA + k0);
    if (vB) aB = *(const bf16x8*)(apB + k0);
    const int sb = (k0 >> 3) + q;             // linear slot for this lane
    #pragma unroll
    for (int t = 0; t < 8; ++t){
      const u16* bp = Bs + (size_t)(t * 16 + m) * K + (size_t)(sb ^ mh) * 8;
      bf16x8 b = *(const bf16x8*)bp;
      acc[0][t] = __builtin_amdgcn_mfma_f32_16x16x32_bf16(aA, b, acc[0][t], 0, 0, 0);
      acc[1][t] = __builtin_amdgcn_mfma_f32_16x16x32_bf16(aB, b, acc[1][t], 0, 0, 0);
    }
  }

  // ---- fused CSR position pass: issue atomics early, consume at end ----
  int ce0 = 0, ce1 = 0, cp0 = 0, cp1 = 0;
  bool cb0 = false, cb1 = false;
  if (do_csr){
    const int nbk = gridDim.x * 4;            // y=2, z=2 on the l1 launch
    const int bid = ((blockIdx.z * 2 + blockIdx.y) * gridDim.x) + blockIdx.x;
    const int epb = (Etot + nbk - 1) / nbk;
    const int elo = bid * epb;
    const int ehi = min(elo + epb, Etot);
    ce0 = elo + (int)threadIdx.x;
    ce1 = ce0 + 256;
    cb0 = ce0 < ehi; cb1 = ce1 < ehi;
    int d0 = 0, d1 = 0;
    if (cb0) d0 = edst[ce0];
    if (cb1) d1 = edst[ce1];
    if (cb0) cp0 = atomicAdd(&cur4[(d0 << 2) | (ce0 & 3)], 1);
    if (cb1) cp1 = atomicAdd(&cur4[(d1 << 2) | (ce1 & 3)], 1);
    // rare fallback (epb > 512): handle inline
    for (int e = elo + (int)threadIdx.x + 512; e < ehi; e += 256){
      int dd = edst[e];
      slotp[e] = atomicAdd(&cur4[(dd << 2) | (e & 3)], 1);
    }
  }

  if (blockIdx.z == 0){
    float alv[8], arv[8];
    #pragma unroll
    for (int t = 0; t < 8; ++t){
      alv[t] = bf2f(al[col0 + t * 16 + m]);
      arv[t] = bf2f(ar[col0 + t * 16 + m]);
    }
    #pragma unroll
    for (int g = 0; g < 2; ++g)
      #pragma unroll
      for (int r = 0; r < 4; ++r){
        float pe[2] = {0.f, 0.f}, pr[2] = {0.f, 0.f};
        #pragma unroll
        for (int t = 0; t < 8; ++t){
          pe[t >> 2] += acc[g][t][r] * alv[t];
          pr[t >> 2] += acc[g][t][r] * arv[t];
        }
        #pragma unroll
        for (int mk = 1; mk < 16; mk <<= 1){
          pe[0] += __shfl_xor(pe[0], mk); pe[1] += __shfl_xor(pe[1], mk);
          pr[0] += __shfl_xor(pr[0], mk); pr[1] += __shfl_xor(pr[1], mk);
        }
        int rr = row0 + g * 16 + q * 4 + r;
        if (m == 0 && rr < N){
          *(float2*)(el4 + (size_t)rr * 4 + blockIdx.y * 2) = make_float2(pe[0], pe[1]);
          *(float2*)(er4 + (size_t)rr * 4 + blockIdx.y * 2) = make_float2(pr[0], pr[1]);
        }
      }
    #pragma unroll
    for (int g = 0; g < 2; ++g)
      #pragma unroll
      for (int t = 0; t < 8; ++t){
        int col = col0 + t * 16 + m;
        #pragma unroll
        for (int r = 0; r < 4; ++r){
          int rr = row0 + g * 16 + q * 4 + r;
          if (rr < N) FT8[(size_t)rr * 256 + col] = f2fp8(acc[g][t][r]);
        }
      }
  } else {
    #pragma unroll
    for (int g = 0; g < 2; ++g)
      #pragma unroll
      for (int t = 0; t < 8; ++t){
        int col = col0 + t * 16 + m;
        #pragma unroll
        for (int r = 0; r < 4; ++r){
          int rr = row0 + g * 16 + q * 4 + r;
          if (rr < N) XA[(size_t)rr * 256 + col] = f2bf(acc[g][t][r]);
        }
      }
  }

  if (do_csr){
    if (cb0) slotp[ce0] = cp0;
    if (cb1) slotp[ce1] = cp1;
  }
}

// ---------------- aggregation v8: 4 dsts/wave, single-pass deferred norm ------
__global__ __launch_bounds__(256) void aggregate8(
    const u8* __restrict__ ft8, const float* __restrict__ el4, const float* __restrict__ er4,
    const int* __restrict__ rowptr, const int* __restrict__ csrs,
    const u16* __restrict__ residb, u16* __restrict__ outb,
    u16* __restrict__ hf, int do_hf, int N)
{
  __shared__ float sal[4][4][17][4];   // [wave][group][edge(+pad)][head]
  __shared__ int   sof[4][4][16];
  const int w = threadIdx.x >> 6, lane = threadIdx.x & 63;
  const int g = lane >> 4, t = lane & 15;
  const int hd = t >> 2;
  const int d = blockIdx.x * 16 + w * 4 + g;
  const bool vd = d < N;
  int beg = 0, deg = 0;
  if (vd){ beg = rowptr[d]; deg = rowptr[d + 1] - beg; }
  int mdeg = deg;
  mdeg = max(mdeg, __shfl_xor(mdeg, 16));
  mdeg = max(mdeg, __shfl_xor(mdeg, 32));
  float4 erd = make_float4(0.f, 0.f, 0.f, 0.f);
  if (vd) erd = ((const float4*)er4)[d];

  f32x2 acc2[8];
  #pragma unroll
  for (int i = 0; i < 8; ++i) acc2[i] = (f32x2){0.f, 0.f};
  float den[4] = {0.f, 0.f, 0.f, 0.f};

  for (int c0 = 0; c0 < mdeg; c0 += 16){
    const int rem = deg - c0;                 // may be <=0 for this group
    // ---- phase A: one edge per lane; raw exp weights + den accumulate ----
    float t0 = 0.f, t1 = 0.f, t2 = 0.f, t3 = 0.f; int s = 0;
    if (t < rem){
      s = csrs[beg + c0 + t];
      float4 ql = ((const float4*)el4)[s];
      float e0 = ql.x + erd.x; e0 = (e0 > 0.f) ? e0 : 0.2f * e0;
      float e1 = ql.y + erd.y; e1 = (e1 > 0.f) ? e1 : 0.2f * e1;
      float e2 = ql.z + erd.z; e2 = (e2 > 0.f) ? e2 : 0.2f * e2;
      float e3 = ql.w + erd.w; e3 = (e3 > 0.f) ? e3 : 0.2f * e3;
      t0 = __expf(fminf(e0, 60.f)); t1 = __expf(fminf(e1, 60.f));
      t2 = __expf(fminf(e2, 60.f)); t3 = __expf(fminf(e3, 60.f));
    }
    den[0] += t0; den[1] += t1; den[2] += t2; den[3] += t3;
    sal[w][g][t][0] = t0; sal[w][g][t][1] = t1;
    sal[w][g][t][2] = t2; sal[w][g][t][3] = t3;
    sof[w][g][t] = s << 8;                    // byte offset of fp8 row
    __builtin_amdgcn_wave_barrier();
    // ---- phase B: 4 edges/iter, 4 gathers in flight ----
    int cr = rem < 16 ? (rem < 0 ? 0 : rem) : 16;
    int jm = (cr + 3) & ~3;
    for (int j = 0; j < jm; j += 4){
      float a[4]; unsigned off[4]; uint4 v[4];
      #pragma unroll
      for (int u = 0; u < 4; ++u){
        a[u] = sal[w][g][j + u][hd];
        off[u] = (unsigned)sof[w][g][j + u];
      }
      #pragma unroll
      for (int u = 0; u < 4; ++u)
        v[u] = *(const uint4*)(ft8 + (size_t)off[u] + t * 16);
      #pragma unroll
      for (int u = 0; u < 4; ++u){
        f32x2 a2 = (f32x2){a[u], a[u]};
        acc2[0] += __builtin_amdgcn_cvt_pk_f32_fp8(v[u].x, 0) * a2;
        acc2[1] += __builtin_amdgcn_cvt_pk_f32_fp8(v[u].x, 1) * a2;
        acc2[2] += __builtin_amdgcn_cvt_pk_f32_fp8(v[u].y, 0) * a2;
        acc2[3] += __builtin_amdgcn_cvt_pk_f32_fp8(v[u].y, 1) * a2;
        acc2[4] += __builtin_amdgcn_cvt_pk_f32_fp8(v[u].z, 0) * a2;
        acc2[5] += __builtin_amdgcn_cvt_pk_f32_fp8(v[u].z, 1) * a2;
        acc2[6] += __builtin_amdgcn_cvt_pk_f32_fp8(v[u].w, 0) * a2;
        acc2[7] += __builtin_amdgcn_cvt_pk_f32_fp8(v[u].w, 1) * a2;
      }
    }
    __builtin_amdgcn_wave_barrier();
  }
  // den reduce within 16-lane group (xor 1,2,4,8 stays in-group)
  #pragma unroll
  for (int mk = 1; mk < 16; mk <<= 1){
    den[0] += __shfl_xor(den[0], mk); den[1] += __shfl_xor(den[1], mk);
    den[2] += __shfl_xor(den[2], mk); den[3] += __shfl_xor(den[3], mk);
  }
  const float dh = den[hd];
  const float inv = (dh > 0.f) ? (1.f / dh) : 0.f;

  if (!vd) return;
  // resid: 16 bf16 = 32B per lane
  const u16* rp = residb + (size_t)d * 256 + t * 16;
  uint4 r0 = *(const uint4*)rp;
  uint4 r1 = *(const uint4*)(rp + 8);
  float o[16];
  {
    union { unsigned u; float f; } x;
    unsigned rw[8] = {r0.x, r0.y, r0.z, r0.w, r1.x, r1.y, r1.z, r1.w};
    #pragma unroll
    for (int i = 0; i < 8; ++i){
      x.u = rw[i] << 16;          o[2 * i]     = x.f;
      x.u = rw[i] & 0xffff0000u;  o[2 * i + 1] = x.f;
    }
  }
  #pragma unroll
  for (int i = 0; i < 8; ++i){
    o[2 * i]     += acc2[i].x * inv;
    o[2 * i + 1] += acc2[i].y * inv;
  }
  if (!do_hf){
    uint4 a, b;
    a.x = pkbf(fmaxf(o[0], 0.f),  fmaxf(o[1], 0.f));
    a.y = pkbf(fmaxf(o[2], 0.f),  fmaxf(o[3], 0.f));
    a.z = pkbf(fmaxf(o[4], 0.f),  fmaxf(o[5], 0.f));
    a.w = pkbf(fmaxf(o[6], 0.f),  fmaxf(o[7], 0.f));
    b.x = pkbf(fmaxf(o[8], 0.f),  fmaxf(o[9], 0.f));
    b.y = pkbf(fmaxf(o[10], 0.f), fmaxf(o[11], 0.f));
    b.z = pkbf(fmaxf(o[12], 0.f), fmaxf(o[13], 0.f));
    b.w = pkbf(fmaxf(o[14], 0.f), fmaxf(o[15], 0.f));
    u16* op = outb + (size_t)d * 256 + t * 16;
    *(uint4*)op = a;
    *(uint4*)(op + 8) = b;
  } else {
    // head-mean: cols k,k+64,k+128,k+192 live at lanes t0,t0+4,t0+8,t0+12
    #pragma unroll
    for (int i = 0; i < 16; ++i){
      float v = o[i];
      v += __shfl_xor(v, 4);
      v += __shfl_xor(v, 8);
      o[i] = 0.25f * v;
    }
    if (t < 4){
      uint4 a, b;
      a.x = pkbf(o[0], o[1]);   a.y = pkbf(o[2], o[3]);
      a.z = pkbf(o[4], o[5]);   a.w = pkbf(o[6], o[7]);
      b.x = pkbf(o[8], o[9]);   b.y = pkbf(o[10], o[11]);
      b.z = pkbf(o[12], o[13]); b.w = pkbf(o[14], o[15]);
      u16* hp = hf + (size_t)d * 64 + t * 16;
      *(uint4*)hp = a;
      *(uint4*)(hp + 8) = b;
    }
  }
}

// ---------------- MFMA edge MLP, CSR-ordered ----------------------------------
__global__ __launch_bounds__(256) void edge_mlp_csr(
    const u16* __restrict__ hfb, const int4* __restrict__ csrp,
    const u16* __restrict__ Wm1, const u16* __restrict__ bm1,
    const u16* __restrict__ Wm2, const u16* __restrict__ bm2,
    void* __restrict__ out, int E, const int* __restrict__ flag)
{
  const int lane = threadIdx.x & 63;
  const int m = lane & 15;
  const int q = lane >> 4;
  const int is_f32 = *flag;

  bf16x8 bfr[4][2];
  #pragma unroll
  for (int t = 0; t < 4; ++t)
    #pragma unroll
    for (int ks = 0; ks < 2; ++ks)
      #pragma unroll
      for (int j = 0; j < 8; ++j)
        bfr[t][ks][j] = (short)Wm1[(size_t)(ks * 32 + q * 8 + j) * 64 + t * 16 + m];

  float b1v[4], w2v[4];
  #pragma unroll
  for (int t = 0; t < 4; ++t){
    b1v[t] = bf2f(bm1[t * 16 + m]);
    w2v[t] = bf2f(Wm2[t * 16 + m]);
  }
  const float b2 = bf2f(bm2[0]);

  const int wid = blockIdx.x * 4 + (threadIdx.x >> 6);
  const int nw  = gridDim.x * 4;
  for (int e0 = wid * 16; e0 < E; e0 += nw * 16){
    int e = e0 + m; if (e >= E) e = E - 1;
    int4 ed = csrp[e];
    const u16* ps = hfb + (size_t)ed.x * 64;
    const u16* pd = hfb + (size_t)ed.y * 64;
    union { bf16x8 v; uint4 u; } af[2];
    #pragma unroll
    for (int ks = 0; ks < 2; ++ks){
      bf16x8 vs = *(const bf16x8*)(ps + ks * 32 + q * 8);
      bf16x8 vd = *(const bf16x8*)(pd + ks * 32 + q * 8);
      unsigned pk[4];
      #pragma unroll
      for (int pp = 0; pp < 4; ++pp){
        float a0 = fabsf(bf2f((u16)vs[2 * pp])     - bf2f((u16)vd[2 * pp]));
        float a1 = fabsf(bf2f((u16)vs[2 * pp + 1]) - bf2f((u16)vd[2 * pp + 1]));
        pk[pp] = pkbf(a0, a1);
      }
      af[ks].u = make_uint4(pk[0], pk[1], pk[2], pk[3]);
    }
    f32x4 acc[4];
    #pragma unroll
    for (int t = 0; t < 4; ++t) acc[t] = (f32x4){0.f, 0.f, 0.f, 0.f};
    #pragma unroll
    for (int ks = 0; ks < 2; ++ks)
      #pragma unroll
      for (int t = 0; t < 4; ++t)
        acc[t] = __builtin_amdgcn_mfma_f32_16x16x32_bf16(af[ks].v, bfr[t][ks], acc[t], 0, 0, 0);
    #pragma unroll
    for (int r = 0; r < 4; ++r){
      float p = 0.f;
      #pragma unroll
      for (int t = 0; t < 4; ++t)
        p += fmaxf(acc[t][r] + b1v[t], 0.f) * w2v[t];
      #pragma unroll
      for (int mm = 1; mm < 16; mm <<= 1) p += __shfl_xor(p, mm);
      int slot = e0 + q * 4 + r;
      if (m == 0 && slot < E){
        int eid = csrp[slot].z;
        float sc = 1.f / (1.f + __expf(-(p + b2)));
        if (is_f32) ((float*)out)[eid] = sc;
        else        ((u16*)out)[eid]   = f2bf(sc);
      }
    }
  }
}

extern "C" void kernel_launch(void* const* d_in, const int* in_sizes, int n_in,
                              void* d_out, int out_size, void* d_ws, size_t ws_size,
                              hipStream_t stream)
{
  const int* src = (const int*)d_in[1];
  const int* dst = (const int*)d_in[2];

  const int N = in_sizes[0] / 128;
  const int E = in_sizes[1];

  char* p = (char*)d_ws;
  auto alloc = [&](size_t bytes) -> char* {
    char* r = p; p += (bytes + 255) & ~(size_t)255; return r;
  };
  int* flag   = (int*)  alloc(4);
  u16* hc     = (u16*)  alloc((size_t)N * 128 * 2);
  u8*  FT8    = (u8*)   alloc((size_t)N * 256);
  u16* XA     = (u16*)  alloc((size_t)N * 256 * 2);
  u16* XB     = (u16*)  alloc((size_t)N * 256 * 2);
  float* el   = (float*)alloc((size_t)N * 4 * 4);
  float* er   = (float*)alloc((size_t)N * 4 * 4);
  u16* hfb    = (u16*)  alloc((size_t)N * 64 * 2);
  int* rowptr = (int*)  alloc((size_t)(N + 1) * 4);
  int* cur4   = (int*)  alloc((size_t)N * 16);       // 4 replica counters/bases
  int* slot   = (int*)  alloc((size_t)E * 4);
  int4* csrp  = (int4*) alloc((size_t)E * 16);
  int* csrs   = (int*)  alloc((size_t)E * 4);
  int* bsums  = (int*)  alloc(1024);
  u16* WT1    = (u16*)  alloc(128 * 256 * 2);
  u16* WTr1   = (u16*)  alloc(128 * 256 * 2);
  u16* WT2    = (u16*)  alloc(256 * 256 * 2);
  u16* WT3    = (u16*)  alloc(256 * 256 * 2);
  u16* al1c   = (u16*)  alloc(256 * 2);
  u16* ar1c   = (u16*)  alloc(256 * 2);
  u16* al2c   = (u16*)  alloc(256 * 2);
  u16* ar2c   = (u16*)  alloc(256 * 2);
  u16* al3c   = (u16*)  alloc(256 * 2);
  u16* ar3c   = (u16*)  alloc(256 * 2);
  u16* Wm1c   = (u16*)  alloc(4096 * 2);
  u16* bm1c   = (u16*)  alloc(64 * 2);
  u16* Wm2c   = (u16*)  alloc(64 * 2);
  u16* bm2c   = (u16*)  alloc(2);

  const int nb = (N + 255) / 256;
  const int ge = (E + 255) / 256;
  const u16* hsrc = (const u16*)d_in[0];

  // flag for edge_mlp's output dtype (nothing else depends on it)
  k_sniff<<<1, 256, 0, stream>>>(hsrc, flag);
  hipMemsetAsync(cur4, 0, (size_t)N * 16, stream);

  // merged prep: canon + LDS transposes (atomic pass moved into gemm_l1)
  {
    Prep16 t{};
    int b = 0;
    auto put = [&](int idx, const void* s, void* d, void* d2, int n, int K,
                   int mode, int nblk){
      t.e[idx] = {s, d, d2, n, K, mode, b};
      b += nblk;
    };
    put(0,  d_in[0],  hc,    nullptr, N * 32,   0,   1, 768);   // h canon (uint2)
    put(1,  d_in[3],  WT1,   nullptr, 0,        128, 2, 32);
    put(2,  d_in[4],  WTr1,  nullptr, 0,        128, 2, 32);
    put(3,  d_in[7],  WT2,   nullptr, 0,        256, 2, 64);
    put(4,  d_in[10], WT3,   nullptr, 0,        256, 2, 64);
    put(5,  d_in[5],  al1c,  nullptr, 256,      0,   0, 1);
    put(6,  d_in[6],  ar1c,  nullptr, 256,      0,   0, 1);
    put(7,  d_in[8],  al2c,  nullptr, 256,      0,   0, 1);
    put(8,  d_in[9],  ar2c,  nullptr, 256,      0,   0, 1);
    put(9,  d_in[11], al3c,  nullptr, 256,      0,   0, 1);
    put(10, d_in[12], ar3c,  nullptr, 256,      0,   0, 1);
    put(11, d_in[13], Wm1c,  nullptr, 4096,     0,   0, 1);
    put(12, d_in[14], bm1c,  nullptr, 64,       0,   0, 1);
    put(13, d_in[15], Wm2c,  nullptr, 64,       0,   0, 1);
    put(14, d_in[16], bm2c,  nullptr, 1,        0,   0, 1);
    put(15, nullptr,  nullptr, nullptr, 0,      0,   0, 0);     // sentinel
    k_prep<<<dim3(b), 256, 0, stream>>>(t, hsrc);
  }

  const dim3 gA3((N + 127) / 128, 2);
  const dim3 gL1((N + 127) / 128, 2, 2);
  const int gG = (N + 15) / 16;
  const int lds1 = 128 * 128 * 2;   // K=128 B-tile
  const int lds2 = 128 * 256 * 2;   // K=256 B-tile

  // layer 1 GEMMs + fused CSR position pass (atomics hidden under MFMA)
  mfma_gemm_v5<<<gL1, 256, lds1, stream>>>(hc, WT1, WTr1, FT8, XA, al1c, ar1c,
                                           el, er, N, 128, dst, slot, cur4, E, 1);
  // CSR scans + atomic-free placement (rowptr/csrp ready before aggregate)
  k_scan1<<<nb, 256, 0, stream>>>((int4*)cur4, rowptr, bsums, N);
  k_scan2<<<1, 256, 0, stream>>>(bsums, nb);
  k_scan3<<<nb, 256, 0, stream>>>(rowptr, bsums, N);
  k_place<<<512, 256, 0, stream>>>(src, dst, slot, rowptr, cur4, csrp, E);
  k_extract<<<ge, 256, 0, stream>>>(csrp, csrs, E);

  aggregate8<<<gG, 256, 0, stream>>>(FT8, el, er, rowptr, csrs, XA, XB, nullptr, 0, N);
  // layer 2
  mfma_gemm_v5<<<gA3, 256, lds2, stream>>>(XB, WT2, WT2, FT8, XA, al2c, ar2c,
                                           el, er, N, 256, nullptr, nullptr, nullptr, 0, 0);
  aggregate8<<<gG, 256, 0, stream>>>(FT8, el, er, rowptr, csrs, XB, XA, nullptr, 0, N);
  // layer 3 (fused head-mean -> hf bf16)
  mfma_gemm_v5<<<gA3, 256, lds2, stream>>>(XA, WT3, WT3, FT8, XB, al3c, ar3c,
                                           el, er, N, 256, nullptr, nullptr, nullptr, 0, 0);
  aggregate8<<<gG, 256, 0, stream>>>(FT8, el, er, rowptr, csrs, XA, nullptr, hfb, 1, N);
  // edge MLP (MFMA, CSR-ordered for dst-row locality)
  edge_mlp_csr<<<2048, 256, 0, stream>>>(hfb, csrp, Wm1c, bm1c, Wm2c, bm2c,
                                         d_out, E, flag);
}